// Round 6
// baseline (1210.211 us; speedup 1.0000x reference)
//
#include <hip/hip_runtime.h>
#include <cstddef>

typedef unsigned int uint;
typedef unsigned short ushort;

// ---- problem constants (from reference) ----
constexpr int BATCH = 2;
constexpr int SEQ   = 2523;
constexpr int CDIM  = 768;
constexpr int NH    = 12;
constexpr int HD    = 64;
constexpr int NM    = 1682;               // template rows
constexpr int NMEM  = 4096;
constexpr int NFULL = NMEM + SEQ;         // 6619
constexpr int NFT   = 6656;               // vT padded row stride
constexpr int TOPM  = 841;                // int(0.50*1682)
constexpr int TOPS  = 1654;               // int(0.25*6619)
constexpr int IDC   = CDIM + NH;          // 780

// selection-key quantization (round 1: 8192x spreads sigma over ~10-18
// hi-buckets -> conflict-free histogram atomics; clamp +-4 is >7 sigma)
constexpr float QSC  = 8192.f;
constexpr float QINV = 1.f/8192.f;

using bf16x8 = __attribute__((ext_vector_type(8))) short;
using f32x4  = __attribute__((ext_vector_type(4))) float;

__device__ __forceinline__ float bf2f(ushort u){ return __uint_as_float(((uint)u) << 16); }
__device__ __forceinline__ ushort f2bf(float f){
  uint x = __float_as_uint(f);
  x += 0x7fffu + ((x >> 16) & 1u);        // RNE
  return (ushort)(x >> 16);
}
// 16-bit monotone selection key from score (float-side clamp -> v_med3_f32)
__device__ __forceinline__ uint qkey(float s){
  float c = fminf(fmaxf(s * QSC, -32768.f), 32767.f);
  int q16 = __float2int_rn(c);
  return ((uint)(ushort)(short)q16) ^ 0x8000u;
}

// ======================= dtype detector =======================
__global__ void detect_mode(const uint* __restrict__ w, int* __restrict__ mode){
  __shared__ int cnt;
  if (threadIdx.x == 0) cnt = 0;
  __syncthreads();
  uint v = w[threadIdx.x * 97];
  uint e = (v >> 7) & 0xFFu;
  if (e >= 100u && e <= 135u) atomicAdd(&cnt, 1);
  __syncthreads();
  if (threadIdx.x == 0) mode[0] = (cnt > 128) ? 1 : 0;   // 1 = bf16, 0 = fp32
}

// ======================= fused input conversion =======================
constexpr int NX_  = BATCH*SEQ*CDIM;
constexpr int NID_ = BATCH*NM*CDIM;
constexpr int NW1_ = 3*CDIM*CDIM;
constexpr int NW2_ = CDIM*CDIM;
constexpr int NW3_ = IDC*CDIM;
constexpr int NCONV = NX_ + NID_ + NW1_ + NW2_ + NW3_ + CDIM + IDC;

__global__ void conv_all(const void* __restrict__ x, const void* __restrict__ id,
                         const void* __restrict__ w1, const void* __restrict__ w2,
                         const void* __restrict__ w3, const void* __restrict__ bp,
                         const void* __restrict__ bi,
                         ushort* __restrict__ xb, ushort* __restrict__ idb,
                         ushort* __restrict__ w1b, ushort* __restrict__ w2b,
                         ushort* __restrict__ w3b, float* __restrict__ bpf,
                         float* __restrict__ bif, const int* __restrict__ modep){
  int i = blockIdx.x*256 + threadIdx.x;
  const int mode = modep[0];
  auto cv = [&](const void* s, int j)->ushort{
    return mode ? ((const ushort*)s)[j] : f2bf(((const float*)s)[j]);
  };
  if (i < NX_ ){ xb[i]  = cv(x, i);  return; } i -= NX_;
  if (i < NID_){ idb[i] = cv(id, i); return; } i -= NID_;
  if (i < NW1_){ w1b[i] = cv(w1, i); return; } i -= NW1_;
  if (i < NW2_){ w2b[i] = cv(w2, i); return; } i -= NW2_;
  if (i < NW3_){ w3b[i] = cv(w3, i); return; } i -= NW3_;
  if (i < CDIM){ bpf[i] = mode ? bf2f(((const ushort*)bp)[i]) : ((const float*)bp)[i]; return; } i -= CDIM;
  if (i < IDC ){ bif[i] = mode ? bf2f(((const ushort*)bi)[i]) : ((const float*)bi)[i]; }
}

// mem_k -> kfull head (coalesced) AND mem_v -> vT head (LDS 64x64 transpose),
// fused: one launch, both sides coalesced. 2-way LDS alias = free.
__global__ __launch_bounds__(256)
void conv_mem2(const void* __restrict__ mk, const void* __restrict__ mv,
               ushort* __restrict__ kf, ushort* __restrict__ vT,
               const int* __restrict__ modep){
  __shared__ ushort t[64][65];
  const int bh = blockIdx.y, j0 = blockIdx.x*64;
  const int mode = modep[0];
  const int tx = threadIdx.x & 63, ty = threadIdx.x >> 6;
  #pragma unroll
  for (int rr = 0; rr < 64; rr += 4){
    int j = j0 + rr + ty;
    size_t s = ((size_t)bh*NMEM + j)*HD + tx;
    ushort kv = mode ? ((const ushort*)mk)[s] : f2bf(((const float*)mk)[s]);
    kf[((size_t)bh*NFULL + j)*HD + tx] = kv;
    t[rr+ty][tx] = mode ? ((const ushort*)mv)[s] : f2bf(((const float*)mv)[s]);
  }
  __syncthreads();
  #pragma unroll
  for (int rr = 0; rr < 64; rr += 4){
    int dd = rr + ty;
    vT[((size_t)bh*HD + dd)*NFT + j0 + tx] = t[tx][dd];
  }
}

__global__ __launch_bounds__(256)
void trans_vrow(const ushort* __restrict__ vrow, ushort* __restrict__ vT){
  __shared__ ushort t[64][65];
  const int bh = blockIdx.y, j0 = blockIdx.x*64;
  const int tx = threadIdx.x & 63, ty = threadIdx.x >> 6;
  #pragma unroll
  for (int rr = 0; rr < 64; rr += 4){
    int n = j0 + rr + ty;
    ushort v = 0;                         // zero-pads vT cols [NFULL,NFT)
    if (n < SEQ) v = vrow[((size_t)bh*SEQ + n)*HD + tx];
    t[rr+ty][tx] = v;
  }
  __syncthreads();
  #pragma unroll
  for (int rr = 0; rr < 64; rr += 4){
    int dd = rr + ty;
    vT[((size_t)bh*HD + dd)*NFT + NMEM + j0 + tx] = t[tx][dd];
  }
}

// ======================= GEMM (m97 structure, 128x128 tile) =======================
#define GEMM_PROLOGUE(M_, Nc_, K_) \
  __shared__ ushort As[128][40]; \
  __shared__ ushort Bs[128][40]; \
  const int tid  = threadIdx.x; \
  const int wave = tid >> 6, lane = tid & 63; \
  const int quad = lane >> 4, l16 = lane & 15; \
  const int row0 = blockIdx.x * 128, col0 = blockIdx.y * 128; \
  const int wr = (wave >> 1) * 64, wc = (wave & 1) * 64; \
  f32x4 acc[4][4] = {}; \
  for (int k0 = 0; k0 < (K_); k0 += 32){ \
    __syncthreads(); \
    for (int c = tid; c < 512; c += 256){ \
      int r = c >> 2, ck = c & 3; \
      uint4 v = {0,0,0,0}; \
      int gr = row0 + r; \
      if (gr < (M_)) v = *(const uint4*)(A + (size_t)gr * (K_) + k0 + ck*8); \
      *(uint4*)(&As[r][ck*8]) = v; \
    } \
    for (int c = tid; c < 512; c += 256){ \
      int r = c >> 2, ck = c & 3; \
      uint4 v = {0,0,0,0}; \
      int gc = col0 + r; \
      if (gc < (Nc_)) v = *(const uint4*)(Bw + (size_t)gc * (K_) + k0 + ck*8); \
      *(uint4*)(&Bs[r][ck*8]) = v; \
    } \
    __syncthreads(); \
    bf16x8 af[4], bfr[4]; \
    _Pragma("unroll") \
    for (int i = 0; i < 4; i++) af[i]  = *(const bf16x8*)(&As[wr + 16*i + l16][quad*8]); \
    _Pragma("unroll") \
    for (int j = 0; j < 4; j++) bfr[j] = *(const bf16x8*)(&Bs[wc + 16*j + l16][quad*8]); \
    _Pragma("unroll") \
    for (int i = 0; i < 4; i++) \
      _Pragma("unroll") \
      for (int j = 0; j < 4; j++) \
        acc[i][j] = __builtin_amdgcn_mfma_f32_16x16x32_bf16(af[i], bfr[j], acc[i][j], 0, 0, 0); \
  }
// C/D layout (verified m89/m91): col = lane&15, row = (lane>>4)*4 + reg

__global__ __launch_bounds__(256)
void gemm_idkv(const ushort* __restrict__ A, const ushort* __restrict__ Bw,
               const float* __restrict__ biasf, float* __restrict__ Cf)
{
  constexpr int M = BATCH*NM, Nc = IDC, K = CDIM;
  GEMM_PROLOGUE(M, Nc, K)
  #pragma unroll
  for (int i = 0; i < 4; i++)
    #pragma unroll
    for (int j = 0; j < 4; j++)
      #pragma unroll
      for (int r = 0; r < 4; r++){
        int row = row0 + wr + 16*i + quad*4 + r;
        int col = col0 + wc + 16*j + l16;
        if (row < M && col < Nc)
          Cf[(size_t)row*Nc + col] = acc[i][j][r] + biasf[col];
      }
}

// qkv GEMM + fused epilogue: q->qallb(bf16,scaled), k->kfull tail + kmod + out_km,
// v->vrow (row-major; transposed to vT by trans_vrow) + out_vm.
__global__ __launch_bounds__(256)
void gemm_qkv(const ushort* __restrict__ A, const ushort* __restrict__ Bw,
              const float* __restrict__ idkvf, ushort* __restrict__ qallb,
              ushort* __restrict__ kfull, ushort* __restrict__ vrow,
              ushort* __restrict__ kmod, void* __restrict__ out_base,
              const int* __restrict__ modep)
{
  constexpr int M = BATCH*SEQ, Nc = 3*CDIM, K = CDIM;
  GEMM_PROLOGUE(M, Nc, K)
  const int mode = modep[0];
  constexpr size_t OKM = (size_t)BATCH*SEQ*CDIM;
  constexpr size_t OVM = OKM + (size_t)BATCH*NH*NM*HD;
  #pragma unroll
  for (int i = 0; i < 4; i++)
    #pragma unroll
    for (int j = 0; j < 4; j++)
      #pragma unroll
      for (int r = 0; r < 4; r++){
        int row = row0 + wr + 16*i + quad*4 + r;
        int col = col0 + wc + 16*j + l16;
        if (row < M && col < Nc){
          float v = acc[i][j][r];
          int b = row / SEQ, n = row - b*SEQ;
          if (col < CDIM){
            int h = col >> 6, dd = col & 63;
            qallb[((size_t)(b*NH+h)*SEQ + n)*HD + dd] = f2bf(v * 0.125f);
          } else if (col < 2*CDIM){
            int c = col - CDIM; int h = c >> 6, dd = c & 63;
            size_t bh = (size_t)b*NH + h;
            kfull[(bh*NFULL + NMEM + n)*HD + dd] = f2bf(v);
            if (n < NM){
              float idk = idkvf[((size_t)b*NM + n)*IDC + h];
              float km = v * (1.f + tanhf(idk));
              size_t o = (bh*NM + n)*HD + dd;
              kmod[o] = f2bf(km);
              if (mode) ((ushort*)out_base)[OKM + o] = f2bf(km);
              else      ((float*) out_base)[OKM + o] = km;
            }
          } else {
            int c = col - 2*CDIM; int h = c >> 6, dd = c & 63;
            size_t bh = (size_t)b*NH + h;
            float vv = v;
            if (n < NM){
              vv = v + idkvf[((size_t)b*NM + n)*IDC + NH + c];
              size_t o = (bh*NM + n)*HD + dd;
              if (mode) ((ushort*)out_base)[OVM + o] = f2bf(vv);
              else      ((float*) out_base)[OVM + o] = vv;
            }
            vrow[(bh*SEQ + n)*HD + dd] = f2bf(vv);
          }
        }
      }
}

__global__ __launch_bounds__(256)
void gemm_proj(const ushort* __restrict__ A, const ushort* __restrict__ Bw,
               const float* __restrict__ biasf, void* __restrict__ out_base,
               const int* __restrict__ modep)
{
  constexpr int M = BATCH*SEQ, Nc = CDIM, K = CDIM;
  GEMM_PROLOGUE(M, Nc, K)
  const int mode = modep[0];
  #pragma unroll
  for (int i = 0; i < 4; i++)
    #pragma unroll
    for (int j = 0; j < 4; j++)
      #pragma unroll
      for (int r = 0; r < 4; r++){
        int row = row0 + wr + 16*i + quad*4 + r;
        int col = col0 + wc + 16*j + l16;
        if (row < M && col < Nc){
          float v = acc[i][j][r] + biasf[col];
          size_t o = (size_t)row*Nc + col;
          if (mode) ((ushort*)out_base)[o] = f2bf(v);
          else      ((float*) out_base)[o] = v;
        }
      }
}

// ======================= slab-free MFMA top-k attention =======================
// 32 q-rows per WG. Scores RECOMPUTED via MFMA per phase (bitwise-identical).
// Round-6 occupancy plan (round-3 lesson: cap WITHOUT trimming live state ->
// 32+ hot regs spilled; this time trim first, then cap):
//  * no K-prefetch double-buffer (-16 regs; K is L2/L3-resident, TLP covers)
//  * pass-3 per-row constants (tk,jc,tv: 24 regs) live in LDS, re-read per
//    tile via volatile (defeats re-hoisting into registers)
//  * full-tile / tail-tile split: hot loop has NO jj<Kn checks or clamps
//  => est. peak ~110-120 regs; __launch_bounds__(256,4) caps at 128 ->
//     4 blocks/CU (LDS 35.3K also allows 4). Spill tripwire: WRITE_SIZE.

struct KFrags { bf16x8 a[2][2]; };      // [g][k-half]

__device__ __forceinline__ void load_kfrags2(const ushort* __restrict__ Kb, int Kn,
                                             int j0, int l16, int quad, bool tail,
                                             KFrags& kf)
{
  #pragma unroll
  for (int g = 0; g < 2; g++){
    int jj = j0 + g*16 + l16;
    int jc = tail ? (jj < Kn ? jj : Kn-1) : jj;
    const ushort* kr = Kb + (size_t)jc*HD + quad*8;
    kf.a[g][0] = *(const bf16x8*)(kr);
    kf.a[g][1] = *(const bf16x8*)(kr + 32);
  }
}

__device__ __forceinline__ void score_mfma(const bf16x8 afr[2][2], const KFrags& kf,
                                           f32x4 cg[2][2])
{
  __builtin_amdgcn_s_setprio(1);
  #pragma unroll
  for (int g = 0; g < 2; g++){
    f32x4 c0 = {}, c1 = {};
    c0 = __builtin_amdgcn_mfma_f32_16x16x32_bf16(afr[0][0], kf.a[g][0], c0, 0,0,0);
    c0 = __builtin_amdgcn_mfma_f32_16x16x32_bf16(afr[0][1], kf.a[g][1], c0, 0,0,0);
    c1 = __builtin_amdgcn_mfma_f32_16x16x32_bf16(afr[1][0], kf.a[g][0], c1, 0,0,0);
    c1 = __builtin_amdgcn_mfma_f32_16x16x32_bf16(afr[1][1], kf.a[g][1], c1, 0,0,0);
    cg[0][g] = c0; cg[1][g] = c1;
  }
  __builtin_amdgcn_s_setprio(0);
}

constexpr int QT_T   = (NM + 31) / 32;          // 53
constexpr int QT_S   = (SEQ - NM + 31) / 32;    // 27
constexpr int NBLK_S = BATCH*NH*QT_S;           // 648  (long blocks first)
constexpr int NBLK_T = BATCH*NH*QT_T;           // 1272

// packed 2-rows-per-word histogram: word index (row&15)*257 + bucket,
// half select row>>4. Counts < 2^16 (Kn<=6619) so no carry.
constexpr int HISTW = 16*257;                   // 4112 words
constexpr int UBUFW = HISTW + 32*64;            // + tie list = 6160 words

__global__ __launch_bounds__(256, 4)
void attn_fused(const ushort* __restrict__ qallb, const ushort* __restrict__ kfull,
                const ushort* __restrict__ kmod,  const ushort* __restrict__ vT,
                ushort* __restrict__ xcat)
{
  __shared__ uint ubuf[UBUFW];          // packed hist | lst 32x64 | (late) redf 2048 f32
  __shared__ ushort Pt[4][32][36];      // per-wave P transpose tile [wave][jl][row]
  __shared__ float zpart[32][4];
  __shared__ uint hi8[32], needs[32], cnts[32];
  __shared__ uint tkjc[32];             // (tk16<<16) | (jcut+1)
  __shared__ float etv[32];             // threshold value (float)
  uint* lst = ubuf + HISTW;
  float* redf = (float*)ubuf;

  const int tid = threadIdx.x;
  const int wave = tid >> 6, lane = tid & 63;
  const int quad = lane >> 4, l16 = lane & 15;

  // ---- fused dispatch: search blocks [0,648), template blocks [648,1920) ----
  int it = blockIdx.x;
  const ushort* Kb; int Kn, ksel, vjoff, qbase, nqtot, bh, qt;
  if (it < NBLK_S){
    bh = it / QT_S; qt = it % QT_S;
    Kn = NFULL; ksel = TOPS; vjoff = 0; qbase = NM; nqtot = SEQ - NM;
    Kb = kfull + (size_t)bh * NFULL * HD;
  } else {
    it -= NBLK_S;
    bh = it / QT_T; qt = it % QT_T;
    Kn = NM; ksel = TOPM; vjoff = NMEM; qbase = 0; nqtot = NM;
    Kb = kmod + (size_t)bh * NM * HD;
  }
  const int b = bh / NH, h = bh % NH;
  const int q0 = qt * 32;
  const int nq = min(32, nqtot - q0);
  const ushort* qb  = qallb + (size_t)bh * SEQ * HD;
  const ushort* vTb = vT + (size_t)bh * HD * NFT + vjoff;

  // tail-tile bookkeeping: tile t = j0/32; wave handles t%4==wave.
  const bool  has_tail  = (Kn & 31) != 0;
  const bool  my_tail   = has_tail && (((Kn >> 5) & 3) == wave);
  const int   tail_j0   = Kn & ~31;

  bf16x8 afr[2][2];
  #pragma unroll
  for (int qf = 0; qf < 2; qf++)
    #pragma unroll
    for (int ds = 0; ds < 2; ds++){
      int qg = qbase + q0 + qf*16 + l16;
      if (qg > SEQ-1) qg = SEQ-1;
      afr[qf][ds] = *(const bf16x8*)(qb + (size_t)qg*HD + ds*32 + quad*8);
    }

  // ---------- pass 1: hi-byte histogram (packed) ----------
  for (int i = tid; i < UBUFW; i += 256) ubuf[i] = 0;
  __syncthreads();
  {
    auto p1 = [&](int j0, bool tail){
      KFrags kc; load_kfrags2(Kb, Kn, j0, l16, quad, tail, kc);
      f32x4 cg[2][2];
      score_mfma(afr, kc, cg);
      #pragma unroll
      for (int qf = 0; qf < 2; qf++){
        const uint inc = 1u << (16*qf);
        #pragma unroll
        for (int g = 0; g < 2; g++){
          if (!tail || (j0 + g*16 + l16) < Kn){
            #pragma unroll
            for (int r = 0; r < 4; r++){
              uint key = qkey(cg[qf][g][r]);
              atomicAdd(&ubuf[(quad*4 + r)*257 + (key>>8)], inc);
            }
          }
        }
      }
    };
    for (int j0 = wave*32; j0 + 32 <= Kn; j0 += 128) p1(j0, false);
    if (my_tail) p1(tail_j0, true);
  }
  __syncthreads();
  if (tid < 32){
    const uint sh = 16*(tid>>4);
    const uint* hrow = ubuf + (tid&15)*257;
    uint need = (uint)ksel, cum = 0; int bsel = 0;
    for (int bb = 255; bb >= 0; bb--){
      uint hc = (hrow[bb] >> sh) & 0xffffu;
      if (cum + hc >= need){ bsel = bb; need -= cum; break; }
      cum += hc;
    }
    hi8[tid] = (uint)bsel; needs[tid] = need;
  }
  __syncthreads();
  for (int i = tid; i < UBUFW; i += 256) ubuf[i] = 0;
  if (tid < 32) cnts[tid] = 0;
  __syncthreads();

  // hoist per-row boundary buckets into registers for pass 2
  uint hi8q[2][4];
  #pragma unroll
  for (int qf = 0; qf < 2; qf++)
    #pragma unroll
    for (int r = 0; r < 4; r++)
      hi8q[qf][r] = hi8[qf*16 + quad*4 + r];

  // ---------- pass 2: lo-byte histogram of boundary bucket + tie list ----------
  {
    auto p2 = [&](int j0, bool tail){
      KFrags kc; load_kfrags2(Kb, Kn, j0, l16, quad, tail, kc);
      f32x4 cg[2][2];
      score_mfma(afr, kc, cg);
      #pragma unroll
      for (int qf = 0; qf < 2; qf++){
        const uint inc = 1u << (16*qf);
        #pragma unroll
        for (int g = 0; g < 2; g++){
          int jj = j0 + g*16 + l16;
          if (!tail || jj < Kn){
            #pragma unroll
            for (int r = 0; r < 4; r++){
              int r15 = quad*4 + r;
              uint key = qkey(cg[qf][g][r]);
              if ((key>>8) == hi8q[qf][r]){
                int row = qf*16 + r15;
                atomicAdd(&ubuf[r15*257 + (key&255u)], inc);
                uint pos = atomicAdd(&cnts[row], 1u);
                if (pos < 64u) lst[row*64 + pos] = ((key&255u)<<16) | (uint)jj;
              }
            }
          }
        }
      }
    };
    for (int j0 = wave*32; j0 + 32 <= Kn; j0 += 128) p2(j0, false);
    if (my_tail) p2(tail_j0, true);
  }
  __syncthreads();
  if (tid < 32){
    const uint sh = 16*(tid>>4);
    const uint* hrow = ubuf + (tid&15)*257;
    uint need = needs[tid], cum = 0; int bsel = 0;
    for (int bb = 255; bb >= 0; bb--){
      uint hc = (hrow[bb] >> sh) & 0xffffu;
      if (cum + hc >= need){ bsel = bb; need -= cum; break; }
      cum += hc;
    }
    uint tk16 = (hi8[tid]<<8) | (uint)bsel;
    uint n = cnts[tid];
    int jc;
    if (n > 64u) jc = Kn;               // overflow fallback: take all ties
    else {
      jc = -1;
      for (uint t = 0; t < need; t++){
        int mn = 0x7fffffff;
        for (uint i2 = 0; i2 < n; i2++){
          uint e = lst[tid*64 + i2];
          if ((e>>16) == (uint)bsel){
            int j = (int)(e & 0xFFFFu);
            if (j > jc && j < mn) mn = j;
          }
        }
        if (mn == 0x7fffffff) break;
        jc = mn;
      }
    }
    tkjc[tid] = (tk16 << 16) | (uint)(jc + 1);   // jc in [-1,Kn], Kn<2^16-1
    etv[tid]  = (float)(short)(ushort)(tk16 ^ 0x8000u) * QINV;
  }
  __syncthreads();

  // ---------- pass 3: P + AV MFMA + Z ----------
  f32x4 oacc[2][4] = {};
  float zacc[2][4] = {};
  {
    volatile uint*  vtk = tkjc;    // volatile: keep per-row consts in LDS, not regs
    volatile float* vet = etv;
    auto p3 = [&](int j0, bool tail){
      KFrags kc; load_kfrags2(Kb, Kn, j0, l16, quad, tail, kc);
      f32x4 cg[2][2];
      score_mfma(afr, kc, cg);
      // form P (bf16) into wave-private transpose tile
      #pragma unroll
      for (int qf = 0; qf < 2; qf++){
        uint w4[4]; float tv4[4];
        #pragma unroll
        for (int r = 0; r < 4; r++){
          int row = qf*16 + quad*4 + r;
          w4[r] = vtk[row]; tv4[r] = vet[row];
        }
        #pragma unroll
        for (int g = 0; g < 2; g++){
          int jj = j0 + g*16 + l16;
          bool inr = !tail || (jj < Kn);
          ushort4 pk;
          ushort* pku = (ushort*)&pk;
          #pragma unroll
          for (int r = 0; r < 4; r++){
            float e = 0.f;
            uint tk = w4[r] >> 16;
            int  jc = (int)(w4[r] & 0xffffu) - 1;
            if (inr){
              float s = cg[qf][g][r];
              uint key = qkey(s);
              if (key > tk || (key == tk && jj <= jc)){
                e = __expf(s - tv4[r]);
                zacc[qf][r] += e;
              }
            }
            pku[r] = f2bf(e);
          }
          *(ushort4*)(&Pt[wave][g*16 + l16][qf*16 + quad*4]) = pk;
        }
      }
      // AV: A = P (rows 16 x jl 32), B = vT (jl 32 x dd 16) -- V loaded inline
      bf16x8 pa[2];
      #pragma unroll
      for (int qf = 0; qf < 2; qf++){
        union { bf16x8 v; ushort u[8]; } pu;
        #pragma unroll
        for (int e = 0; e < 8; e++) pu.u[e] = Pt[wave][quad*8 + e][qf*16 + l16];
        pa[qf] = pu.v;
      }
      __builtin_amdgcn_s_setprio(1);
      #pragma unroll
      for (int df = 0; df < 4; df++){
        bf16x8 bv = *(const bf16x8*)(vTb + (size_t)(df*16 + l16)*NFT + j0 + quad*8);
        oacc[0][df] = __builtin_amdgcn_mfma_f32_16x16x32_bf16(pa[0], bv, oacc[0][df], 0,0,0);
        oacc[1][df] = __builtin_amdgcn_mfma_f32_16x16x32_bf16(pa[1], bv, oacc[1][df], 0,0,0);
      }
      __builtin_amdgcn_s_setprio(0);
    };
    for (int j0 = wave*32; j0 + 32 <= Kn; j0 += 128) p3(j0, false);
    if (my_tail) p3(tail_j0, true);
    // tail AV reads vT cols up to (Kn&~31)+31 < NFT (zero-padded); P=0 there.
  }

  // Z: reduce across the 16 j-lanes, then across waves
  #pragma unroll
  for (int qf = 0; qf < 2; qf++)
    #pragma unroll
    for (int r = 0; r < 4; r++){
      float v = zacc[qf][r];
      #pragma unroll
      for (int mk = 1; mk < 16; mk <<= 1) v += __shfl_xor(v, mk);
      if (l16 == 0) zpart[qf*16 + quad*4 + r][wave] = v;
    }
  __syncthreads();

  // O: sequential cross-wave reduction into redf (reuses ubuf)
  for (int w = 0; w < 4; w++){
    if (wave == w){
      #pragma unroll
      for (int qf = 0; qf < 2; qf++)
        #pragma unroll
        for (int df = 0; df < 4; df++)
          #pragma unroll
          for (int r = 0; r < 4; r++){
            int idx = (qf*16 + quad*4 + r)*64 + df*16 + l16;
            if (w == 0) redf[idx]  = oacc[qf][df][r];
            else        redf[idx] += oacc[qf][df][r];
          }
    }
    __syncthreads();
  }

  // store
  {
    int row = tid >> 3, d0 = (tid & 7) * 8;
    if (row < nq){
      float Z = zpart[row][0] + zpart[row][1] + zpart[row][2] + zpart[row][3];
      float zinv = Z > 0.f ? 1.f/Z : 0.f;
      uint4 ov; ushort* op = (ushort*)&ov;
      #pragma unroll
      for (int e = 0; e < 8; e++) op[e] = f2bf(redf[row*64 + d0 + e] * zinv);
      int qg = qbase + q0 + row;
      *(uint4*)(xcat + ((size_t)b*SEQ + qg)*CDIM + h*HD + d0) = ov;
    }
  }
}

// ======================= launch =======================
extern "C" void kernel_launch(void* const* d_in, const int* in_sizes, int n_in,
                              void* d_out, int out_size, void* d_ws, size_t ws_size,
                              hipStream_t stream)
{
  const void* x        = d_in[0];
  const void* id_total = d_in[1];
  const void* mem_k    = d_in[2];
  const void* mem_v    = d_in[3];
  const void* w_qkv    = d_in[4];
  const void* w_proj   = d_in[5];
  const void* b_proj   = d_in[6];
  const void* w_idkv   = d_in[7];
  const void* b_idkv   = d_in[8];

  char* p = (char*)d_ws;
  auto carve = [&](size_t bytes)->char*{
    char* q = p; p += (bytes + 255) & ~(size_t)255; return q;
  };
  int*    modep  = (int*)   carve(256);
  ushort* xb     = (ushort*)carve(2ull*BATCH*SEQ*CDIM);
  ushort* idb    = (ushort*)carve(2ull*BATCH*NM*CDIM);
  ushort* wqkvb  = (ushort*)carve(2ull*3*CDIM*CDIM);
  ushort* wprojb = (ushort*)carve(2ull*CDIM*CDIM);
  ushort* widkvb = (ushort*)carve(2ull*IDC*CDIM);
  float*  bprojf = (float*) carve(4ull*CDIM);
  float*  bidkvf = (float*) carve(4ull*IDC);
  float*  idkvf  = (float*) carve(4ull*BATCH*NM*IDC);
  ushort* qallb  = (ushort*)carve(2ull*BATCH*NH*SEQ*HD);
  ushort* kfull  = (ushort*)carve(2ull*BATCH*NH*NFULL*HD);
  ushort* vT     = (ushort*)carve(2ull*BATCH*NH*HD*NFT);
  ushort* kmod   = (ushort*)carve(2ull*BATCH*NH*NM*HD);
  ushort* xcat   = (ushort*)carve(2ull*BATCH*SEQ*CDIM);
  ushort* vrow   = (ushort*)carve(2ull*BATCH*NH*SEQ*HD);

  dim3 blk(256,1,1);

  hipLaunchKernelGGL(detect_mode, dim3(1), blk, 0, stream, (const uint*)w_qkv, modep);
  hipLaunchKernelGGL(conv_all, dim3((NCONV+255)/256), blk, 0, stream,
                     x, id_total, w_qkv, w_proj, w_idkv, b_proj, b_idkv,
                     xb, idb, wqkvb, wprojb, widkvb, bprojf, bidkvf, modep);
  hipLaunchKernelGGL(conv_mem2, dim3(NMEM/64, BATCH*NH), blk, 0, stream,
                     mem_k, mem_v, kfull, vT, modep);
  {
    int M = BATCH*NM, Nc = IDC;
    dim3 grid((M+127)/128, (Nc+127)/128, 1);
    hipLaunchKernelGGL(gemm_idkv, grid, blk, 0, stream, idb, widkvb, bidkvf, idkvf);
  }
  {
    int M = BATCH*SEQ, Nc = 3*CDIM;
    dim3 grid((M+127)/128, (Nc+127)/128, 1);
    hipLaunchKernelGGL(gemm_qkv, grid, blk, 0, stream,
                       xb, wqkvb, idkvf, qallb, kfull, vrow, kmod, d_out, modep);
  }
  hipLaunchKernelGGL(trans_vrow, dim3((NFT-NMEM)/64, BATCH*NH), blk, 0, stream,
                     vrow, vT);
  { // fused template+search attention; long-running search blocks dispatched first
    hipLaunchKernelGGL(attn_fused, dim3(NBLK_S + NBLK_T), blk, 0, stream,
                       qallb, kfull, kmod, vT, xcat);
  }
  {
    int M = BATCH*SEQ, Nc = CDIM;
    dim3 grid((M+127)/128, (Nc+127)/128, 1);
    hipLaunchKernelGGL(gemm_proj, grid, blk, 0, stream, xcat, wprojb, bprojf, d_out, modep);
  }
}

// Round 7
// 1130.531 us; speedup vs baseline: 1.0705x; 1.0705x over previous
//
#include <hip/hip_runtime.h>
#include <cstddef>

typedef unsigned int uint;
typedef unsigned short ushort;

// ---- problem constants (from reference) ----
constexpr int BATCH = 2;
constexpr int SEQ   = 2523;
constexpr int CDIM  = 768;
constexpr int NH    = 12;
constexpr int HD    = 64;
constexpr int NM    = 1682;               // template rows
constexpr int NMEM  = 4096;
constexpr int NFULL = NMEM + SEQ;         // 6619
constexpr int NFT   = 6656;               // vT padded row stride
constexpr int TOPM  = 841;                // int(0.50*1682)
constexpr int TOPS  = 1654;               // int(0.25*6619)
constexpr int IDC   = CDIM + NH;          // 780

// selection-key quantization (round 1: 8192x spreads sigma over ~10-18
// hi-buckets -> conflict-free histogram atomics; clamp +-4 is >7 sigma)
constexpr float QSC  = 8192.f;
constexpr float QINV = 1.f/8192.f;

using bf16x8 = __attribute__((ext_vector_type(8))) short;
using f32x4  = __attribute__((ext_vector_type(4))) float;
using f32x16 = __attribute__((ext_vector_type(16))) float;

__device__ __forceinline__ float bf2f(ushort u){ return __uint_as_float(((uint)u) << 16); }
__device__ __forceinline__ ushort f2bf(float f){
  uint x = __float_as_uint(f);
  x += 0x7fffu + ((x >> 16) & 1u);        // RNE
  return (ushort)(x >> 16);
}
// 16-bit monotone selection key from score (float-side clamp -> v_med3_f32)
__device__ __forceinline__ uint qkey(float s){
  float c = fminf(fmaxf(s * QSC, -32768.f), 32767.f);
  int q16 = __float2int_rn(c);
  return ((uint)(ushort)(short)q16) ^ 0x8000u;
}

// ======================= dtype detector =======================
__global__ void detect_mode(const uint* __restrict__ w, int* __restrict__ mode){
  __shared__ int cnt;
  if (threadIdx.x == 0) cnt = 0;
  __syncthreads();
  uint v = w[threadIdx.x * 97];
  uint e = (v >> 7) & 0xFFu;
  if (e >= 100u && e <= 135u) atomicAdd(&cnt, 1);
  __syncthreads();
  if (threadIdx.x == 0) mode[0] = (cnt > 128) ? 1 : 0;   // 1 = bf16, 0 = fp32
}

// ======================= fused input conversion =======================
constexpr int NX_  = BATCH*SEQ*CDIM;
constexpr int NID_ = BATCH*NM*CDIM;
constexpr int NW1_ = 3*CDIM*CDIM;
constexpr int NW2_ = CDIM*CDIM;
constexpr int NW3_ = IDC*CDIM;
constexpr int NCONV = NX_ + NID_ + NW1_ + NW2_ + NW3_ + CDIM + IDC;

__global__ void conv_all(const void* __restrict__ x, const void* __restrict__ id,
                         const void* __restrict__ w1, const void* __restrict__ w2,
                         const void* __restrict__ w3, const void* __restrict__ bp,
                         const void* __restrict__ bi,
                         ushort* __restrict__ xb, ushort* __restrict__ idb,
                         ushort* __restrict__ w1b, ushort* __restrict__ w2b,
                         ushort* __restrict__ w3b, float* __restrict__ bpf,
                         float* __restrict__ bif, const int* __restrict__ modep){
  int i = blockIdx.x*256 + threadIdx.x;
  const int mode = modep[0];
  auto cv = [&](const void* s, int j)->ushort{
    return mode ? ((const ushort*)s)[j] : f2bf(((const float*)s)[j]);
  };
  if (i < NX_ ){ xb[i]  = cv(x, i);  return; } i -= NX_;
  if (i < NID_){ idb[i] = cv(id, i); return; } i -= NID_;
  if (i < NW1_){ w1b[i] = cv(w1, i); return; } i -= NW1_;
  if (i < NW2_){ w2b[i] = cv(w2, i); return; } i -= NW2_;
  if (i < NW3_){ w3b[i] = cv(w3, i); return; } i -= NW3_;
  if (i < CDIM){ bpf[i] = mode ? bf2f(((const ushort*)bp)[i]) : ((const float*)bp)[i]; return; } i -= CDIM;
  if (i < IDC ){ bif[i] = mode ? bf2f(((const ushort*)bi)[i]) : ((const float*)bi)[i]; }
}

// mem_k -> kfull head (coalesced) AND mem_v -> vT head (LDS 64x64 transpose)
__global__ __launch_bounds__(256)
void conv_mem2(const void* __restrict__ mk, const void* __restrict__ mv,
               ushort* __restrict__ kf, ushort* __restrict__ vT,
               const int* __restrict__ modep){
  __shared__ ushort t[64][65];
  const int bh = blockIdx.y, j0 = blockIdx.x*64;
  const int mode = modep[0];
  const int tx = threadIdx.x & 63, ty = threadIdx.x >> 6;
  #pragma unroll
  for (int rr = 0; rr < 64; rr += 4){
    int j = j0 + rr + ty;
    size_t s = ((size_t)bh*NMEM + j)*HD + tx;
    ushort kv = mode ? ((const ushort*)mk)[s] : f2bf(((const float*)mk)[s]);
    kf[((size_t)bh*NFULL + j)*HD + tx] = kv;
    t[rr+ty][tx] = mode ? ((const ushort*)mv)[s] : f2bf(((const float*)mv)[s]);
  }
  __syncthreads();
  #pragma unroll
  for (int rr = 0; rr < 64; rr += 4){
    int dd = rr + ty;
    vT[((size_t)bh*HD + dd)*NFT + j0 + tx] = t[tx][dd];
  }
}

__global__ __launch_bounds__(256)
void trans_vrow(const ushort* __restrict__ vrow, ushort* __restrict__ vT){
  __shared__ ushort t[64][65];
  const int bh = blockIdx.y, j0 = blockIdx.x*64;
  const int tx = threadIdx.x & 63, ty = threadIdx.x >> 6;
  #pragma unroll
  for (int rr = 0; rr < 64; rr += 4){
    int n = j0 + rr + ty;
    ushort v = 0;                         // zero-pads vT cols [NFULL,NFT)
    if (n < SEQ) v = vrow[((size_t)bh*SEQ + n)*HD + tx];
    t[rr+ty][tx] = v;
  }
  __syncthreads();
  #pragma unroll
  for (int rr = 0; rr < 64; rr += 4){
    int dd = rr + ty;
    vT[((size_t)bh*HD + dd)*NFT + NMEM + j0 + tx] = t[tx][dd];
  }
}

// ======================= GEMM (m97 structure, 128x128 tile) =======================
#define GEMM_PROLOGUE(M_, Nc_, K_) \
  __shared__ ushort As[128][40]; \
  __shared__ ushort Bs[128][40]; \
  const int tid  = threadIdx.x; \
  const int wave = tid >> 6, lane = tid & 63; \
  const int quad = lane >> 4, l16 = lane & 15; \
  const int row0 = blockIdx.x * 128, col0 = blockIdx.y * 128; \
  const int wr = (wave >> 1) * 64, wc = (wave & 1) * 64; \
  f32x4 acc[4][4] = {}; \
  for (int k0 = 0; k0 < (K_); k0 += 32){ \
    __syncthreads(); \
    for (int c = tid; c < 512; c += 256){ \
      int r = c >> 2, ck = c & 3; \
      uint4 v = {0,0,0,0}; \
      int gr = row0 + r; \
      if (gr < (M_)) v = *(const uint4*)(A + (size_t)gr * (K_) + k0 + ck*8); \
      *(uint4*)(&As[r][ck*8]) = v; \
    } \
    for (int c = tid; c < 512; c += 256){ \
      int r = c >> 2, ck = c & 3; \
      uint4 v = {0,0,0,0}; \
      int gc = col0 + r; \
      if (gc < (Nc_)) v = *(const uint4*)(Bw + (size_t)gc * (K_) + k0 + ck*8); \
      *(uint4*)(&Bs[r][ck*8]) = v; \
    } \
    __syncthreads(); \
    bf16x8 af[4], bfr[4]; \
    _Pragma("unroll") \
    for (int i = 0; i < 4; i++) af[i]  = *(const bf16x8*)(&As[wr + 16*i + l16][quad*8]); \
    _Pragma("unroll") \
    for (int j = 0; j < 4; j++) bfr[j] = *(const bf16x8*)(&Bs[wc + 16*j + l16][quad*8]); \
    _Pragma("unroll") \
    for (int i = 0; i < 4; i++) \
      _Pragma("unroll") \
      for (int j = 0; j < 4; j++) \
        acc[i][j] = __builtin_amdgcn_mfma_f32_16x16x32_bf16(af[i], bfr[j], acc[i][j], 0, 0, 0); \
  }
// C/D layout (verified m89/m91): col = lane&15, row = (lane>>4)*4 + reg

__global__ __launch_bounds__(256)
void gemm_idkv(const ushort* __restrict__ A, const ushort* __restrict__ Bw,
               const float* __restrict__ biasf, float* __restrict__ Cf)
{
  constexpr int M = BATCH*NM, Nc = IDC, K = CDIM;
  GEMM_PROLOGUE(M, Nc, K)
  #pragma unroll
  for (int i = 0; i < 4; i++)
    #pragma unroll
    for (int j = 0; j < 4; j++)
      #pragma unroll
      for (int r = 0; r < 4; r++){
        int row = row0 + wr + 16*i + quad*4 + r;
        int col = col0 + wc + 16*j + l16;
        if (row < M && col < Nc)
          Cf[(size_t)row*Nc + col] = acc[i][j][r] + biasf[col];
      }
}

// qkv GEMM + fused epilogue: q->qallb(bf16,scaled), k->kfull tail + kmod + out_km,
// v->vrow (row-major; transposed to vT by trans_vrow) + out_vm.
__global__ __launch_bounds__(256)
void gemm_qkv(const ushort* __restrict__ A, const ushort* __restrict__ Bw,
              const float* __restrict__ idkvf, ushort* __restrict__ qallb,
              ushort* __restrict__ kfull, ushort* __restrict__ vrow,
              ushort* __restrict__ kmod, void* __restrict__ out_base,
              const int* __restrict__ modep)
{
  constexpr int M = BATCH*SEQ, Nc = 3*CDIM, K = CDIM;
  GEMM_PROLOGUE(M, Nc, K)
  const int mode = modep[0];
  constexpr size_t OKM = (size_t)BATCH*SEQ*CDIM;
  constexpr size_t OVM = OKM + (size_t)BATCH*NH*NM*HD;
  #pragma unroll
  for (int i = 0; i < 4; i++)
    #pragma unroll
    for (int j = 0; j < 4; j++)
      #pragma unroll
      for (int r = 0; r < 4; r++){
        int row = row0 + wr + 16*i + quad*4 + r;
        int col = col0 + wc + 16*j + l16;
        if (row < M && col < Nc){
          float v = acc[i][j][r];
          int b = row / SEQ, n = row - b*SEQ;
          if (col < CDIM){
            int h = col >> 6, dd = col & 63;
            qallb[((size_t)(b*NH+h)*SEQ + n)*HD + dd] = f2bf(v * 0.125f);
          } else if (col < 2*CDIM){
            int c = col - CDIM; int h = c >> 6, dd = c & 63;
            size_t bh = (size_t)b*NH + h;
            kfull[(bh*NFULL + NMEM + n)*HD + dd] = f2bf(v);
            if (n < NM){
              float idk = idkvf[((size_t)b*NM + n)*IDC + h];
              float km = v * (1.f + tanhf(idk));
              size_t o = (bh*NM + n)*HD + dd;
              kmod[o] = f2bf(km);
              if (mode) ((ushort*)out_base)[OKM + o] = f2bf(km);
              else      ((float*) out_base)[OKM + o] = km;
            }
          } else {
            int c = col - 2*CDIM; int h = c >> 6, dd = c & 63;
            size_t bh = (size_t)b*NH + h;
            float vv = v;
            if (n < NM){
              vv = v + idkvf[((size_t)b*NM + n)*IDC + NH + c];
              size_t o = (bh*NM + n)*HD + dd;
              if (mode) ((ushort*)out_base)[OVM + o] = f2bf(vv);
              else      ((float*) out_base)[OVM + o] = vv;
            }
            vrow[(bh*SEQ + n)*HD + dd] = f2bf(vv);
          }
        }
      }
}

__global__ __launch_bounds__(256)
void gemm_proj(const ushort* __restrict__ A, const ushort* __restrict__ Bw,
               const float* __restrict__ biasf, void* __restrict__ out_base,
               const int* __restrict__ modep)
{
  constexpr int M = BATCH*SEQ, Nc = CDIM, K = CDIM;
  GEMM_PROLOGUE(M, Nc, K)
  const int mode = modep[0];
  #pragma unroll
  for (int i = 0; i < 4; i++)
    #pragma unroll
    for (int j = 0; j < 4; j++)
      #pragma unroll
      for (int r = 0; r < 4; r++){
        int row = row0 + wr + 16*i + quad*4 + r;
        int col = col0 + wc + 16*j + l16;
        if (row < M && col < Nc){
          float v = acc[i][j][r] + biasf[col];
          size_t o = (size_t)row*Nc + col;
          if (mode) ((ushort*)out_base)[o] = f2bf(v);
          else      ((float*) out_base)[o] = v;
        }
      }
}

// ======================= slab-free MFMA top-k attention =======================
// Round 7: swapped 32x32x16 MFMA (A=K, B=Q). D layout col=lane&31 = q-row,
// row=(reg&3)+8*(reg>>2)+4*(lane>>5) = key. Each lane owns ONE q-row (l32):
//  * histogram/threshold state is lane-local (3 regs, was 24)
//  * P -> AV A-fragment transform is pure VALU: 8 v_cvt_pk_bf16_f32 +
//    4 v_permlane32_swap_b32 (exchanges lane<32/lane>=32 halves). The Pt LDS
//    transpose (8 ds_write_b64 + 16 ds_read_u16/tile, the constant 2e7 bank
//    conflicts of rounds 1-6) is DELETED.
// Hist unpacked (round-2 best config), K prefetch kept, no occupancy cap.

struct KF32 { bf16x8 c[4]; };           // A-operand K fragments, 4 k-chunks

__device__ __forceinline__ void load_k32(const ushort* __restrict__ Kb, int Kn,
                                         int j0, int l32, int h, bool tail, KF32& kf)
{
  int jj = j0 + l32;
  int jc = tail ? (jj < Kn ? jj : Kn-1) : jj;
  const ushort* kr = Kb + (size_t)jc*HD + h*8;
  #pragma unroll
  for (int c = 0; c < 4; c++) kf.c[c] = *(const bf16x8*)(kr + c*16);
}

__device__ __forceinline__ f32x16 score32(const bf16x8 bq[4], const KF32& kf)
{
  f32x16 acc = {};
  __builtin_amdgcn_s_setprio(1);
  #pragma unroll
  for (int c = 0; c < 4; c++)
    acc = __builtin_amdgcn_mfma_f32_32x32x16_bf16(kf.c[c], bq[c], acc, 0, 0, 0);
  __builtin_amdgcn_s_setprio(0);
  return acc;
}

__device__ __forceinline__ uint cvtpk_bf16(float lo, float hi){
  uint d;
  asm("v_cvt_pk_bf16_f32 %0, %1, %2" : "=v"(d) : "v"(lo), "v"(hi));
  return d;
}

constexpr int QT_T   = (NM + 31) / 32;          // 53
constexpr int QT_S   = (SEQ - NM + 31) / 32;    // 27
constexpr int NBLK_S = BATCH*NH*QT_S;           // 648  (long blocks first)
constexpr int NBLK_T = BATCH*NH*QT_T;           // 1272

constexpr int HISTW = 32*257;                   // unpacked, 8224 words
constexpr int UBUFW = HISTW + 32*64;            // + tie list = 10272 words

__global__ __launch_bounds__(256)
void attn_fused(const ushort* __restrict__ qallb, const ushort* __restrict__ kfull,
                const ushort* __restrict__ kmod,  const ushort* __restrict__ vT,
                ushort* __restrict__ xcat)
{
  __shared__ uint ubuf[UBUFW];          // hist 32x257 | lst 32x64 | (late) redf 2048 f32
  __shared__ float zpart[32][4];
  __shared__ uint hi8[32], needs[32], tks[32], cnts[32];
  __shared__ int jcuts[32];
  uint* lst = ubuf + HISTW;
  float* redf = (float*)ubuf;

  const int tid = threadIdx.x;
  const int wave = tid >> 6, lane = tid & 63;
  const int l32 = lane & 31, h = lane >> 5;

  // ---- fused dispatch: search blocks [0,648), template blocks [648,1920) ----
  int it = blockIdx.x;
  const ushort* Kb; int Kn, ksel, vjoff, qbase, nqtot, bh, qt;
  if (it < NBLK_S){
    bh = it / QT_S; qt = it % QT_S;
    Kn = NFULL; ksel = TOPS; vjoff = 0; qbase = NM; nqtot = SEQ - NM;
    Kb = kfull + (size_t)bh * NFULL * HD;
  } else {
    it -= NBLK_S;
    bh = it / QT_T; qt = it % QT_T;
    Kn = NM; ksel = TOPM; vjoff = NMEM; qbase = 0; nqtot = NM;
    Kb = kmod + (size_t)bh * NM * HD;
  }
  const int b = bh / NH, hh = bh % NH;
  const int q0 = qt * 32;
  const int nq = min(32, nqtot - q0);
  const ushort* qb  = qallb + (size_t)bh * SEQ * HD;
  const ushort* vTb = vT + (size_t)bh * HD * NFT + vjoff;

  // tail-tile bookkeeping: tile t = j0/32 handled by wave t%4
  const bool  has_tail = (Kn & 31) != 0;
  const bool  my_tail  = has_tail && (((Kn >> 5) & 3) == wave);
  const int   tail_j0  = Kn & ~31;

  // Q fragment (B operand): lane holds Q[q=l32][k = c*16 + h*8 + e]
  bf16x8 bq[4];
  {
    int qg = qbase + q0 + l32;
    if (qg > SEQ-1) qg = SEQ-1;
    const ushort* qr = qb + (size_t)qg*HD + h*8;
    #pragma unroll
    for (int c = 0; c < 4; c++) bq[c] = *(const bf16x8*)(qr + c*16);
  }

  // ---------- pass 1: hi-byte histogram ----------
  for (int i = tid; i < UBUFW; i += 256) ubuf[i] = 0;
  __syncthreads();
  {
    auto p1 = [&](int j0, bool tail, const KF32& kc){
      f32x16 acc = score32(bq, kc);
      #pragma unroll
      for (int s = 0; s < 4; s++)
        #pragma unroll
        for (int r = 0; r < 4; r++){
          if (!tail || (j0 + r + 8*s + 4*h) < Kn){
            uint key = qkey(acc[s*4+r]);
            atomicAdd(&ubuf[l32*257 + (key>>8)], 1u);
          }
        }
    };
    KF32 kc, kn2;
    load_k32(Kb, Kn, wave*32, l32, h, false, kc);
    int j0 = wave*32;
    for (; j0 + 160 <= Kn; j0 += 128){            // next full tile exists
      load_k32(Kb, Kn, j0+128, l32, h, false, kn2);
      p1(j0, false, kc);
      kc = kn2;
    }
    if (j0 + 32 <= Kn) p1(j0, false, kc);
    if (my_tail){
      KF32 kt; load_k32(Kb, Kn, tail_j0, l32, h, true, kt);
      p1(tail_j0, true, kt);
    }
  }
  __syncthreads();
  if (tid < 32){
    const uint* hrow = ubuf + tid*257;
    uint need = (uint)ksel, cum = 0; int bsel = 0;
    for (int bb = 255; bb >= 0; bb--){
      uint hc = hrow[bb];
      if (cum + hc >= need){ bsel = bb; need -= cum; break; }
      cum += hc;
    }
    hi8[tid] = (uint)bsel; needs[tid] = need;
  }
  __syncthreads();
  for (int i = tid; i < UBUFW; i += 256) ubuf[i] = 0;
  if (tid < 32) cnts[tid] = 0;
  __syncthreads();

  const uint hi8q = hi8[l32];

  // ---------- pass 2: lo-byte histogram of boundary bucket + tie list ----------
  {
    auto p2 = [&](int j0, bool tail, const KF32& kc){
      f32x16 acc = score32(bq, kc);
      #pragma unroll
      for (int s = 0; s < 4; s++)
        #pragma unroll
        for (int r = 0; r < 4; r++){
          int jj = j0 + r + 8*s + 4*h;
          if (!tail || jj < Kn){
            uint key = qkey(acc[s*4+r]);
            if ((key>>8) == hi8q){
              atomicAdd(&ubuf[l32*257 + (key&255u)], 1u);
              uint pos = atomicAdd(&cnts[l32], 1u);
              if (pos < 64u) lst[l32*64 + pos] = ((key&255u)<<16) | (uint)jj;
            }
          }
        }
    };
    KF32 kc, kn2;
    load_k32(Kb, Kn, wave*32, l32, h, false, kc);
    int j0 = wave*32;
    for (; j0 + 160 <= Kn; j0 += 128){
      load_k32(Kb, Kn, j0+128, l32, h, false, kn2);
      p2(j0, false, kc);
      kc = kn2;
    }
    if (j0 + 32 <= Kn) p2(j0, false, kc);
    if (my_tail){
      KF32 kt; load_k32(Kb, Kn, tail_j0, l32, h, true, kt);
      p2(tail_j0, true, kt);
    }
  }
  __syncthreads();
  if (tid < 32){
    const uint* hrow = ubuf + tid*257;
    uint need = needs[tid], cum = 0; int bsel = 0;
    for (int bb = 255; bb >= 0; bb--){
      uint hc = hrow[bb];
      if (cum + hc >= need){ bsel = bb; need -= cum; break; }
      cum += hc;
    }
    tks[tid] = (hi8[tid]<<8) | (uint)bsel;
    uint n = cnts[tid];
    int jc;
    if (n > 64u) jc = Kn;               // overflow fallback: take all ties
    else {
      jc = -1;
      for (uint t = 0; t < need; t++){
        int mn = 0x7fffffff;
        for (uint i2 = 0; i2 < n; i2++){
          uint e = lst[tid*64 + i2];
          if ((e>>16) == (uint)bsel){
            int j = (int)(e & 0xFFFFu);
            if (j > jc && j < mn) mn = j;
          }
        }
        if (mn == 0x7fffffff) break;
        jc = mn;
      }
    }
    jcuts[tid] = jc;
  }
  __syncthreads();

  // ---------- pass 3: P + AV MFMA + Z ----------
  f32x16 oc0 = {}, oc1 = {};
  float zacc = 0.f;
  const uint  tkv = tks[l32];
  const int   jcv = jcuts[l32];
  const float tvv = (float)(short)(ushort)(tkv ^ 0x8000u) * QINV;
  {
    auto p3 = [&](int j0, bool tail, const KF32& kc){
      f32x16 acc = score32(bq, kc);
      // masked exp -> packed bf16 pairs (pk[2s] = keys{r0,r1}, pk[2s+1] = {r2,r3})
      uint pk[8];
      #pragma unroll
      for (int s = 0; s < 4; s++){
        float ev[4];
        #pragma unroll
        for (int r = 0; r < 4; r++){
          float e = 0.f;
          int jj = j0 + r + 8*s + 4*h;
          if (!tail || jj < Kn){
            float sc = acc[s*4+r];
            uint key = qkey(sc);
            if (key > tkv || (key == tkv && jj <= jcv)){
              e = __expf(sc - tvv);
              zacc += e;
            }
          }
          ev[r] = e;
        }
        pk[2*s]   = cvtpk_bf16(ev[0], ev[1]);
        pk[2*s+1] = cvtpk_bf16(ev[2], ev[3]);
      }
      // half-wave exchange: after swap(X,Y): X=[X_lo|Y_lo], Y=[X_hi|Y_hi]
      uint a0 = pk[0], b0 = pk[2];
      asm("v_permlane32_swap_b32 %0, %1" : "+v"(a0), "+v"(b0));
      uint a1 = pk[1], b1 = pk[3];
      asm("v_permlane32_swap_b32 %0, %1" : "+v"(a1), "+v"(b1));
      uint a2 = pk[4], b2 = pk[6];
      asm("v_permlane32_swap_b32 %0, %1" : "+v"(a2), "+v"(b2));
      uint a3 = pk[5], b3 = pk[7];
      asm("v_permlane32_swap_b32 %0, %1" : "+v"(a3), "+v"(b3));
      union U8 { bf16x8 v; uint u[4]; } A0, A1;
      A0.u[0] = a0; A0.u[1] = a1; A0.u[2] = b0; A0.u[3] = b1;  // j chunk [j0, j0+16)
      A1.u[0] = a2; A1.u[1] = a3; A1.u[2] = b2; A1.u[3] = b3;  // j chunk [j0+16, j0+32)
      // AV: B[dd=l32(+32*ddg)][j = h*8+e]; D row = q, col = dd
      const ushort* v0 = vTb + (size_t)l32*NFT + j0 + h*8;
      const ushort* v1 = vTb + (size_t)(32 + l32)*NFT + j0 + h*8;
      bf16x8 bv00 = *(const bf16x8*)(v0);
      bf16x8 bv01 = *(const bf16x8*)(v0 + 16);
      bf16x8 bv10 = *(const bf16x8*)(v1);
      bf16x8 bv11 = *(const bf16x8*)(v1 + 16);
      __builtin_amdgcn_s_setprio(1);
      oc0 = __builtin_amdgcn_mfma_f32_32x32x16_bf16(A0.v, bv00, oc0, 0,0,0);
      oc0 = __builtin_amdgcn_mfma_f32_32x32x16_bf16(A1.v, bv01, oc0, 0,0,0);
      oc1 = __builtin_amdgcn_mfma_f32_32x32x16_bf16(A0.v, bv10, oc1, 0,0,0);
      oc1 = __builtin_amdgcn_mfma_f32_32x32x16_bf16(A1.v, bv11, oc1, 0,0,0);
      __builtin_amdgcn_s_setprio(0);
    };
    KF32 kc, kn2;
    load_k32(Kb, Kn, wave*32, l32, h, false, kc);
    int j0 = wave*32;
    for (; j0 + 160 <= Kn; j0 += 128){
      load_k32(Kb, Kn, j0+128, l32, h, false, kn2);
      p3(j0, false, kc);
      kc = kn2;
    }
    if (j0 + 32 <= Kn) p3(j0, false, kc);
    if (my_tail){
      KF32 kt; load_k32(Kb, Kn, tail_j0, l32, h, true, kt);
      p3(tail_j0, true, kt);
    }
    // tail AV reads vT cols < NFT (zero-padded / masked by P=0); safe.
  }

  // Z: both halves of a row sum via lane^32, then cross-wave
  zacc += __shfl_xor(zacc, 32);
  if (lane < 32) zpart[l32][wave] = zacc;
  __syncthreads();

  // O: sequential cross-wave reduction into redf (reuses ubuf)
  for (int w = 0; w < 4; w++){
    if (wave == w){
      #pragma unroll
      for (int s = 0; s < 4; s++)
        #pragma unroll
        for (int r = 0; r < 4; r++){
          int q = r + 8*s + 4*h;
          int i0 = q*64 + l32;
          if (w == 0){ redf[i0] = oc0[s*4+r];  redf[i0+32] = oc1[s*4+r]; }
          else       { redf[i0] += oc0[s*4+r]; redf[i0+32] += oc1[s*4+r]; }
        }
    }
    __syncthreads();
  }

  // store
  {
    int row = tid >> 3, d0 = (tid & 7) * 8;
    if (row < nq){
      float Z = zpart[row][0] + zpart[row][1] + zpart[row][2] + zpart[row][3];
      float zinv = Z > 0.f ? 1.f/Z : 0.f;
      uint4 ov; ushort* op = (ushort*)&ov;
      #pragma unroll
      for (int e = 0; e < 8; e++) op[e] = f2bf(redf[row*64 + d0 + e] * zinv);
      int qg = qbase + q0 + row;
      *(uint4*)(xcat + ((size_t)b*SEQ + qg)*CDIM + hh*HD + d0) = ov;
    }
  }
}

// ======================= launch =======================
extern "C" void kernel_launch(void* const* d_in, const int* in_sizes, int n_in,
                              void* d_out, int out_size, void* d_ws, size_t ws_size,
                              hipStream_t stream)
{
  const void* x        = d_in[0];
  const void* id_total = d_in[1];
  const void* mem_k    = d_in[2];
  const void* mem_v    = d_in[3];
  const void* w_qkv    = d_in[4];
  const void* w_proj   = d_in[5];
  const void* b_proj   = d_in[6];
  const void* w_idkv   = d_in[7];
  const void* b_idkv   = d_in[8];

  char* p = (char*)d_ws;
  auto carve = [&](size_t bytes)->char*{
    char* q = p; p += (bytes + 255) & ~(size_t)255; return q;
  };
  int*    modep  = (int*)   carve(256);
  ushort* xb     = (ushort*)carve(2ull*BATCH*SEQ*CDIM);
  ushort* idb    = (ushort*)carve(2ull*BATCH*NM*CDIM);
  ushort* wqkvb  = (ushort*)carve(2ull*3*CDIM*CDIM);
  ushort* wprojb = (ushort*)carve(2ull*CDIM*CDIM);
  ushort* widkvb = (ushort*)carve(2ull*IDC*CDIM);
  float*  bprojf = (float*) carve(4ull*CDIM);
  float*  bidkvf = (float*) carve(4ull*IDC);
  float*  idkvf  = (float*) carve(4ull*BATCH*NM*IDC);
  ushort* qallb  = (ushort*)carve(2ull*BATCH*NH*SEQ*HD);
  ushort* kfull  = (ushort*)carve(2ull*BATCH*NH*NFULL*HD);
  ushort* vT     = (ushort*)carve(2ull*BATCH*NH*HD*NFT);
  ushort* kmod   = (ushort*)carve(2ull*BATCH*NH*NM*HD);
  ushort* xcat   = (ushort*)carve(2ull*BATCH*SEQ*CDIM);
  ushort* vrow   = (ushort*)carve(2ull*BATCH*NH*SEQ*HD);

  dim3 blk(256,1,1);

  hipLaunchKernelGGL(detect_mode, dim3(1), blk, 0, stream, (const uint*)w_qkv, modep);
  hipLaunchKernelGGL(conv_all, dim3((NCONV+255)/256), blk, 0, stream,
                     x, id_total, w_qkv, w_proj, w_idkv, b_proj, b_idkv,
                     xb, idb, wqkvb, wprojb, widkvb, bprojf, bidkvf, modep);
  hipLaunchKernelGGL(conv_mem2, dim3(NMEM/64, BATCH*NH), blk, 0, stream,
                     mem_k, mem_v, kfull, vT, modep);
  {
    int M = BATCH*NM, Nc = IDC;
    dim3 grid((M+127)/128, (Nc+127)/128, 1);
    hipLaunchKernelGGL(gemm_idkv, grid, blk, 0, stream, idb, widkvb, bidkvf, idkvf);
  }
  {
    int M = BATCH*SEQ, Nc = 3*CDIM;
    dim3 grid((M+127)/128, (Nc+127)/128, 1);
    hipLaunchKernelGGL(gemm_qkv, grid, blk, 0, stream,
                       xb, wqkvb, idkvf, qallb, kfull, vrow, kmod, d_out, modep);
  }
  hipLaunchKernelGGL(trans_vrow, dim3((NFT-NMEM)/64, BATCH*NH), blk, 0, stream,
                     vrow, vT);
  { // fused template+search attention; long-running search blocks dispatched first
    hipLaunchKernelGGL(attn_fused, dim3(NBLK_S + NBLK_T), blk, 0, stream,
                       qallb, kfull, kmod, vT, xcat);
  }
  {
    int M = BATCH*SEQ, Nc = CDIM;
    dim3 grid((M+127)/128, (Nc+127)/128, 1);
    hipLaunchKernelGGL(gemm_proj, grid, blk, 0, stream, xcat, wprojb, bprojf, d_out, modep);
  }
}

// Round 9
// 1125.087 us; speedup vs baseline: 1.0757x; 1.0048x over previous
//
#include <hip/hip_runtime.h>
#include <cstddef>

typedef unsigned int uint;
typedef unsigned short ushort;

// ---- problem constants (from reference) ----
constexpr int BATCH = 2;
constexpr int SEQ   = 2523;
constexpr int CDIM  = 768;
constexpr int NH    = 12;
constexpr int HD    = 64;
constexpr int NM    = 1682;               // template rows
constexpr int NMEM  = 4096;
constexpr int NFULL = NMEM + SEQ;         // 6619
constexpr int NFT   = 6656;               // vT padded row stride
constexpr int TOPM  = 841;                // int(0.50*1682)
constexpr int TOPS  = 1654;               // int(0.25*6619)
constexpr int IDC   = CDIM + NH;          // 780

// selection-key quantization (round 1: 8192x spreads sigma over ~10-18
// hi-buckets -> conflict-free histogram atomics; clamp +-4 is >7 sigma)
constexpr float QSC  = 8192.f;
constexpr float QINV = 1.f/8192.f;

using bf16x8 = __attribute__((ext_vector_type(8))) short;
using f32x4  = __attribute__((ext_vector_type(4))) float;
using f32x16 = __attribute__((ext_vector_type(16))) float;

__device__ __forceinline__ float bf2f(ushort u){ return __uint_as_float(((uint)u) << 16); }
__device__ __forceinline__ ushort f2bf(float f){
  uint x = __float_as_uint(f);
  x += 0x7fffu + ((x >> 16) & 1u);        // RNE
  return (ushort)(x >> 16);
}
// 16-bit monotone selection key from score (float-side clamp -> v_med3_f32)
__device__ __forceinline__ uint qkey(float s){
  float c = fminf(fmaxf(s * QSC, -32768.f), 32767.f);
  int q16 = __float2int_rn(c);
  return ((uint)(ushort)(short)q16) ^ 0x8000u;
}

// ======================= dtype detector =======================
__global__ void detect_mode(const uint* __restrict__ w, int* __restrict__ mode){
  __shared__ int cnt;
  if (threadIdx.x == 0) cnt = 0;
  __syncthreads();
  uint v = w[threadIdx.x * 97];
  uint e = (v >> 7) & 0xFFu;
  if (e >= 100u && e <= 135u) atomicAdd(&cnt, 1);
  __syncthreads();
  if (threadIdx.x == 0) mode[0] = (cnt > 128) ? 1 : 0;   // 1 = bf16, 0 = fp32
}

// ======================= fused input conversion =======================
constexpr int NX_  = BATCH*SEQ*CDIM;
constexpr int NID_ = BATCH*NM*CDIM;
constexpr int NW1_ = 3*CDIM*CDIM;
constexpr int NW2_ = CDIM*CDIM;
constexpr int NW3_ = IDC*CDIM;
constexpr int NCONV = NX_ + NID_ + NW1_ + NW2_ + NW3_ + CDIM + IDC;

__global__ void conv_all(const void* __restrict__ x, const void* __restrict__ id,
                         const void* __restrict__ w1, const void* __restrict__ w2,
                         const void* __restrict__ w3, const void* __restrict__ bp,
                         const void* __restrict__ bi,
                         ushort* __restrict__ xb, ushort* __restrict__ idb,
                         ushort* __restrict__ w1b, ushort* __restrict__ w2b,
                         ushort* __restrict__ w3b, float* __restrict__ bpf,
                         float* __restrict__ bif, const int* __restrict__ modep){
  int i = blockIdx.x*256 + threadIdx.x;
  const int mode = modep[0];
  auto cv = [&](const void* s, int j)->ushort{
    return mode ? ((const ushort*)s)[j] : f2bf(((const float*)s)[j]);
  };
  if (i < NX_ ){ xb[i]  = cv(x, i);  return; } i -= NX_;
  if (i < NID_){ idb[i] = cv(id, i); return; } i -= NID_;
  if (i < NW1_){ w1b[i] = cv(w1, i); return; } i -= NW1_;
  if (i < NW2_){ w2b[i] = cv(w2, i); return; } i -= NW2_;
  if (i < NW3_){ w3b[i] = cv(w3, i); return; } i -= NW3_;
  if (i < CDIM){ bpf[i] = mode ? bf2f(((const ushort*)bp)[i]) : ((const float*)bp)[i]; return; } i -= CDIM;
  if (i < IDC ){ bif[i] = mode ? bf2f(((const ushort*)bi)[i]) : ((const float*)bi)[i]; }
}

// mem_k -> kfull head (coalesced) AND mem_v -> vT head (LDS 64x64 transpose)
__global__ __launch_bounds__(256)
void conv_mem2(const void* __restrict__ mk, const void* __restrict__ mv,
               ushort* __restrict__ kf, ushort* __restrict__ vT,
               const int* __restrict__ modep){
  __shared__ ushort t[64][65];
  const int bh = blockIdx.y, j0 = blockIdx.x*64;
  const int mode = modep[0];
  const int tx = threadIdx.x & 63, ty = threadIdx.x >> 6;
  #pragma unroll
  for (int rr = 0; rr < 64; rr += 4){
    int j = j0 + rr + ty;
    size_t s = ((size_t)bh*NMEM + j)*HD + tx;
    ushort kv = mode ? ((const ushort*)mk)[s] : f2bf(((const float*)mk)[s]);
    kf[((size_t)bh*NFULL + j)*HD + tx] = kv;
    t[rr+ty][tx] = mode ? ((const ushort*)mv)[s] : f2bf(((const float*)mv)[s]);
  }
  __syncthreads();
  #pragma unroll
  for (int rr = 0; rr < 64; rr += 4){
    int dd = rr + ty;
    vT[((size_t)bh*HD + dd)*NFT + j0 + tx] = t[tx][dd];
  }
}

__global__ __launch_bounds__(256)
void trans_vrow(const ushort* __restrict__ vrow, ushort* __restrict__ vT){
  __shared__ ushort t[64][65];
  const int bh = blockIdx.y, j0 = blockIdx.x*64;
  const int tx = threadIdx.x & 63, ty = threadIdx.x >> 6;
  #pragma unroll
  for (int rr = 0; rr < 64; rr += 4){
    int n = j0 + rr + ty;
    ushort v = 0;                         // zero-pads vT cols [NFULL,NFT)
    if (n < SEQ) v = vrow[((size_t)bh*SEQ + n)*HD + tx];
    t[rr+ty][tx] = v;
  }
  __syncthreads();
  #pragma unroll
  for (int rr = 0; rr < 64; rr += 4){
    int dd = rr + ty;
    vT[((size_t)bh*HD + dd)*NFT + NMEM + j0 + tx] = t[tx][dd];
  }
}

// ======================= GEMM (m97 structure, 128x128 tile) =======================
#define GEMM_PROLOGUE(M_, Nc_, K_) \
  __shared__ ushort As[128][40]; \
  __shared__ ushort Bs[128][40]; \
  const int tid  = threadIdx.x; \
  const int wave = tid >> 6, lane = tid & 63; \
  const int quad = lane >> 4, l16 = lane & 15; \
  const int row0 = blockIdx.x * 128, col0 = blockIdx.y * 128; \
  const int wr = (wave >> 1) * 64, wc = (wave & 1) * 64; \
  f32x4 acc[4][4] = {}; \
  for (int k0 = 0; k0 < (K_); k0 += 32){ \
    __syncthreads(); \
    for (int c = tid; c < 512; c += 256){ \
      int r = c >> 2, ck = c & 3; \
      uint4 v = {0,0,0,0}; \
      int gr = row0 + r; \
      if (gr < (M_)) v = *(const uint4*)(A + (size_t)gr * (K_) + k0 + ck*8); \
      *(uint4*)(&As[r][ck*8]) = v; \
    } \
    for (int c = tid; c < 512; c += 256){ \
      int r = c >> 2, ck = c & 3; \
      uint4 v = {0,0,0,0}; \
      int gc = col0 + r; \
      if (gc < (Nc_)) v = *(const uint4*)(Bw + (size_t)gc * (K_) + k0 + ck*8); \
      *(uint4*)(&Bs[r][ck*8]) = v; \
    } \
    __syncthreads(); \
    bf16x8 af[4], bfr[4]; \
    _Pragma("unroll") \
    for (int i = 0; i < 4; i++) af[i]  = *(const bf16x8*)(&As[wr + 16*i + l16][quad*8]); \
    _Pragma("unroll") \
    for (int j = 0; j < 4; j++) bfr[j] = *(const bf16x8*)(&Bs[wc + 16*j + l16][quad*8]); \
    _Pragma("unroll") \
    for (int i = 0; i < 4; i++) \
      _Pragma("unroll") \
      for (int j = 0; j < 4; j++) \
        acc[i][j] = __builtin_amdgcn_mfma_f32_16x16x32_bf16(af[i], bfr[j], acc[i][j], 0, 0, 0); \
  }
// C/D layout (verified m89/m91): col = lane&15, row = (lane>>4)*4 + reg

__global__ __launch_bounds__(256)
void gemm_idkv(const ushort* __restrict__ A, const ushort* __restrict__ Bw,
               const float* __restrict__ biasf, float* __restrict__ Cf)
{
  constexpr int M = BATCH*NM, Nc = IDC, K = CDIM;
  GEMM_PROLOGUE(M, Nc, K)
  #pragma unroll
  for (int i = 0; i < 4; i++)
    #pragma unroll
    for (int j = 0; j < 4; j++)
      #pragma unroll
      for (int r = 0; r < 4; r++){
        int row = row0 + wr + 16*i + quad*4 + r;
        int col = col0 + wc + 16*j + l16;
        if (row < M && col < Nc)
          Cf[(size_t)row*Nc + col] = acc[i][j][r] + biasf[col];
      }
}

// qkv GEMM + fused epilogue: q->qallb(bf16,scaled), k->kfull tail + kmod + out_km,
// v->vrow (row-major; transposed to vT by trans_vrow) + out_vm.
__global__ __launch_bounds__(256)
void gemm_qkv(const ushort* __restrict__ A, const ushort* __restrict__ Bw,
              const float* __restrict__ idkvf, ushort* __restrict__ qallb,
              ushort* __restrict__ kfull, ushort* __restrict__ vrow,
              ushort* __restrict__ kmod, void* __restrict__ out_base,
              const int* __restrict__ modep)
{
  constexpr int M = BATCH*SEQ, Nc = 3*CDIM, K = CDIM;
  GEMM_PROLOGUE(M, Nc, K)
  const int mode = modep[0];
  constexpr size_t OKM = (size_t)BATCH*SEQ*CDIM;
  constexpr size_t OVM = OKM + (size_t)BATCH*NH*NM*HD;
  #pragma unroll
  for (int i = 0; i < 4; i++)
    #pragma unroll
    for (int j = 0; j < 4; j++)
      #pragma unroll
      for (int r = 0; r < 4; r++){
        int row = row0 + wr + 16*i + quad*4 + r;
        int col = col0 + wc + 16*j + l16;
        if (row < M && col < Nc){
          float v = acc[i][j][r];
          int b = row / SEQ, n = row - b*SEQ;
          if (col < CDIM){
            int h = col >> 6, dd = col & 63;
            qallb[((size_t)(b*NH+h)*SEQ + n)*HD + dd] = f2bf(v * 0.125f);
          } else if (col < 2*CDIM){
            int c = col - CDIM; int h = c >> 6, dd = c & 63;
            size_t bh = (size_t)b*NH + h;
            kfull[(bh*NFULL + NMEM + n)*HD + dd] = f2bf(v);
            if (n < NM){
              float idk = idkvf[((size_t)b*NM + n)*IDC + h];
              float km = v * (1.f + tanhf(idk));
              size_t o = (bh*NM + n)*HD + dd;
              kmod[o] = f2bf(km);
              if (mode) ((ushort*)out_base)[OKM + o] = f2bf(km);
              else      ((float*) out_base)[OKM + o] = km;
            }
          } else {
            int c = col - 2*CDIM; int h = c >> 6, dd = c & 63;
            size_t bh = (size_t)b*NH + h;
            float vv = v;
            if (n < NM){
              vv = v + idkvf[((size_t)b*NM + n)*IDC + NH + c];
              size_t o = (bh*NM + n)*HD + dd;
              if (mode) ((ushort*)out_base)[OVM + o] = f2bf(vv);
              else      ((float*) out_base)[OVM + o] = vv;
            }
            vrow[(bh*SEQ + n)*HD + dd] = f2bf(vv);
          }
        }
      }
}

__global__ __launch_bounds__(256)
void gemm_proj(const ushort* __restrict__ A, const ushort* __restrict__ Bw,
               const float* __restrict__ biasf, void* __restrict__ out_base,
               const int* __restrict__ modep)
{
  constexpr int M = BATCH*SEQ, Nc = CDIM, K = CDIM;
  GEMM_PROLOGUE(M, Nc, K)
  const int mode = modep[0];
  #pragma unroll
  for (int i = 0; i < 4; i++)
    #pragma unroll
    for (int j = 0; j < 4; j++)
      #pragma unroll
      for (int r = 0; r < 4; r++){
        int row = row0 + wr + 16*i + quad*4 + r;
        int col = col0 + wc + 16*j + l16;
        if (row < M && col < Nc){
          float v = acc[i][j][r] + biasf[col];
          size_t o = (size_t)row*Nc + col;
          if (mode) ((ushort*)out_base)[o] = f2bf(v);
          else      ((float*) out_base)[o] = v;
        }
      }
}

// ======================= slab-free MFMA top-k attention =======================
// Round 8 on top of round 7's swapped 32x32 structure:
//  * packed 2-rows/word histogram -- FREE here (lane owns one row, so the
//    pack shift/inc are loop-invariant regs). LDS 42.5K -> ~26K.
//  * XCD-aware block remap: all blocks of a head land on one XCD (xcd=p&7
//    round-robin model); per-head K+vT ~1.7MB fits the 4MB per-XCD L2 across
//    all 3 passes. FETCH_SIZE is the causal test.

struct KF32 { bf16x8 c[4]; };           // A-operand K fragments, 4 k-chunks

__device__ __forceinline__ void load_k32(const ushort* __restrict__ Kb, int Kn,
                                         int j0, int l32, int h, bool tail, KF32& kf)
{
  int jj = j0 + l32;
  int jc = tail ? (jj < Kn ? jj : Kn-1) : jj;
  const ushort* kr = Kb + (size_t)jc*HD + h*8;
  #pragma unroll
  for (int c = 0; c < 4; c++) kf.c[c] = *(const bf16x8*)(kr + c*16);
}

__device__ __forceinline__ f32x16 score32(const bf16x8 bq[4], const KF32& kf)
{
  f32x16 acc = {};
  __builtin_amdgcn_s_setprio(1);
  #pragma unroll
  for (int c = 0; c < 4; c++)
    acc = __builtin_amdgcn_mfma_f32_32x32x16_bf16(kf.c[c], bq[c], acc, 0, 0, 0);
  __builtin_amdgcn_s_setprio(0);
  return acc;
}

__device__ __forceinline__ uint cvtpk_bf16(float lo, float hi){
  uint d;
  asm("v_cvt_pk_bf16_f32 %0, %1, %2" : "=v"(d) : "v"(lo), "v"(hi));
  return d;
}

constexpr int QT_T   = (NM + 31) / 32;          // 53
constexpr int QT_S   = (SEQ - NM + 31) / 32;    // 27
constexpr int NBLK_S = BATCH*NH*QT_S;           // 648  (long blocks first)
constexpr int NBLK_T = BATCH*NH*QT_T;           // 1272
// per-XCD decomposition: 24 heads -> 3 per XCD; 3*27=81 search + 3*53=159
// template = 240 blocks/XCD * 8 = 1920.
constexpr int XS = 3*QT_S;                      // 81

// packed 2-rows-per-word histogram: word (row&15)*257 + bucket, half row>>4.
constexpr int HISTW = 16*257;                   // 4112 words
constexpr int UBUFW = HISTW + 32*64;            // + tie list = 6160 words

__global__ __launch_bounds__(256)
void attn_fused(const ushort* __restrict__ qallb, const ushort* __restrict__ kfull,
                const ushort* __restrict__ kmod,  const ushort* __restrict__ vT,
                ushort* __restrict__ xcat)
{
  __shared__ uint ubuf[UBUFW];          // packed hist | lst 32x64 | (late) redf 2048 f32
  __shared__ float zpart[32][4];
  __shared__ uint hi8[32], needs[32], tks[32], cnts[32];
  __shared__ int jcuts[32];
  uint* lst = ubuf + HISTW;
  float* redf = (float*)ubuf;

  const int tid = threadIdx.x;
  const int wave = tid >> 6, lane = tid & 63;
  const int l32 = lane & 31, h = lane >> 5;

  // ---- XCD-aware remap: physical p -> logical it so each head stays on one XCD
  int it;
  {
    int p = blockIdx.x;
    int xcd = p & 7, k = p >> 3;                // assumed round-robin XCD model
    if (k < XS){ int g = k/QT_S, qt2 = k - g*QT_S; it = (xcd + 8*g)*QT_S + qt2; }
    else { int k2 = k - XS; int g = k2/QT_T, qt2 = k2 - g*QT_T;
           it = NBLK_S + (xcd + 8*g)*QT_T + qt2; }
  }
  const ushort* Kb; int Kn, ksel, vjoff, qbase, nqtot, bh, qt;
  if (it < NBLK_S){
    bh = it / QT_S; qt = it % QT_S;
    Kn = NFULL; ksel = TOPS; vjoff = 0; qbase = NM; nqtot = SEQ - NM;
    Kb = kfull + (size_t)bh * NFULL * HD;
  } else {
    it -= NBLK_S;
    bh = it / QT_T; qt = it % QT_T;
    Kn = NM; ksel = TOPM; vjoff = NMEM; qbase = 0; nqtot = NM;
    Kb = kmod + (size_t)bh * NM * HD;
  }
  const int b = bh / NH, hh = bh % NH;
  const int q0 = qt * 32;
  const int nq = min(32, nqtot - q0);
  const ushort* qb  = qallb + (size_t)bh * SEQ * HD;
  const ushort* vTb = vT + (size_t)bh * HD * NFT + vjoff;

  // tail-tile bookkeeping: tile t = j0/32 handled by wave t%4
  const bool  has_tail = (Kn & 31) != 0;
  const bool  my_tail  = has_tail && (((Kn >> 5) & 3) == wave);
  const int   tail_j0  = Kn & ~31;

  // packed-histogram lane constants (loop-invariant)
  const uint hsh  = 16*(l32>>4);
  const uint hinc = 1u << hsh;
  uint* hrowp = ubuf + (l32&15)*257;

  // Q fragment (B operand): lane holds Q[q=l32][k = c*16 + h*8 + e]
  bf16x8 bq[4];
  {
    int qg = qbase + q0 + l32;
    if (qg > SEQ-1) qg = SEQ-1;
    const ushort* qr = qb + (size_t)qg*HD + h*8;
    #pragma unroll
    for (int c = 0; c < 4; c++) bq[c] = *(const bf16x8*)(qr + c*16);
  }

  // ---------- pass 1: hi-byte histogram (packed) ----------
  for (int i = tid; i < UBUFW; i += 256) ubuf[i] = 0;
  __syncthreads();
  {
    auto p1 = [&](int j0, bool tail, const KF32& kc){
      f32x16 acc = score32(bq, kc);
      #pragma unroll
      for (int s = 0; s < 4; s++)
        #pragma unroll
        for (int r = 0; r < 4; r++){
          if (!tail || (j0 + r + 8*s + 4*h) < Kn){
            uint key = qkey(acc[s*4+r]);
            atomicAdd(hrowp + (key>>8), hinc);
          }
        }
    };
    KF32 kc, kn2;
    load_k32(Kb, Kn, wave*32, l32, h, false, kc);
    int j0 = wave*32;
    for (; j0 + 160 <= Kn; j0 += 128){            // next full tile exists
      load_k32(Kb, Kn, j0+128, l32, h, false, kn2);
      p1(j0, false, kc);
      kc = kn2;
    }
    if (j0 + 32 <= Kn) p1(j0, false, kc);
    if (my_tail){
      KF32 kt; load_k32(Kb, Kn, tail_j0, l32, h, true, kt);
      p1(tail_j0, true, kt);
    }
  }
  __syncthreads();
  if (tid < 32){
    const uint sh = 16*(tid>>4);
    const uint* hrow = ubuf + (tid&15)*257;
    uint need = (uint)ksel, cum = 0; int bsel = 0;
    for (int bb = 255; bb >= 0; bb--){
      uint hc = (hrow[bb] >> sh) & 0xffffu;
      if (cum + hc >= need){ bsel = bb; need -= cum; break; }
      cum += hc;
    }
    hi8[tid] = (uint)bsel; needs[tid] = need;
  }
  __syncthreads();
  for (int i = tid; i < UBUFW; i += 256) ubuf[i] = 0;
  if (tid < 32) cnts[tid] = 0;
  __syncthreads();

  const uint hi8q = hi8[l32];

  // ---------- pass 2: lo-byte histogram of boundary bucket + tie list ----------
  {
    auto p2 = [&](int j0, bool tail, const KF32& kc){
      f32x16 acc = score32(bq, kc);
      #pragma unroll
      for (int s = 0; s < 4; s++)
        #pragma unroll
        for (int r = 0; r < 4; r++){
          int jj = j0 + r + 8*s + 4*h;
          if (!tail || jj < Kn){
            uint key = qkey(acc[s*4+r]);
            if ((key>>8) == hi8q){
              atomicAdd(hrowp + (key&255u), hinc);
              uint pos = atomicAdd(&cnts[l32], 1u);
              if (pos < 64u) lst[l32*64 + pos] = ((key&255u)<<16) | (uint)jj;
            }
          }
        }
    };
    KF32 kc, kn2;
    load_k32(Kb, Kn, wave*32, l32, h, false, kc);
    int j0 = wave*32;
    for (; j0 + 160 <= Kn; j0 += 128){
      load_k32(Kb, Kn, j0+128, l32, h, false, kn2);
      p2(j0, false, kc);
      kc = kn2;
    }
    if (j0 + 32 <= Kn) p2(j0, false, kc);
    if (my_tail){
      KF32 kt; load_k32(Kb, Kn, tail_j0, l32, h, true, kt);
      p2(tail_j0, true, kt);
    }
  }
  __syncthreads();
  if (tid < 32){
    const uint sh = 16*(tid>>4);
    const uint* hrow = ubuf + (tid&15)*257;
    uint need = needs[tid], cum = 0; int bsel = 0;
    for (int bb = 255; bb >= 0; bb--){
      uint hc = (hrow[bb] >> sh) & 0xffffu;
      if (cum + hc >= need){ bsel = bb; need -= cum; break; }
      cum += hc;
    }
    tks[tid] = (hi8[tid]<<8) | (uint)bsel;
    uint n = cnts[tid];
    int jc;
    if (n > 64u) jc = Kn;               // overflow fallback: take all ties
    else {
      jc = -1;
      for (uint t = 0; t < need; t++){
        int mn = 0x7fffffff;
        for (uint i2 = 0; i2 < n; i2++){
          uint e = lst[tid*64 + i2];
          if ((e>>16) == (uint)bsel){
            int j = (int)(e & 0xFFFFu);
            if (j > jc && j < mn) mn = j;
          }
        }
        if (mn == 0x7fffffff) break;
        jc = mn;
      }
    }
    jcuts[tid] = jc;
  }
  __syncthreads();

  // ---------- pass 3: P + AV MFMA + Z ----------
  f32x16 oc0 = {}, oc1 = {};
  float zacc = 0.f;
  const uint  tkv = tks[l32];
  const int   jcv = jcuts[l32];
  const float tvv = (float)(short)(ushort)(tkv ^ 0x8000u) * QINV;
  {
    auto p3 = [&](int j0, bool tail, const KF32& kc){
      f32x16 acc = score32(bq, kc);
      // masked exp -> packed bf16 pairs (pk[2s] = keys{r0,r1}, pk[2s+1] = {r2,r3})
      uint pk[8];
      #pragma unroll
      for (int s = 0; s < 4; s++){
        float ev[4];
        #pragma unroll
        for (int r = 0; r < 4; r++){
          float e = 0.f;
          int jj = j0 + r + 8*s + 4*h;
          if (!tail || jj < Kn){
            float sc = acc[s*4+r];
            uint key = qkey(sc);
            if (key > tkv || (key == tkv && jj <= jcv)){
              e = __expf(sc - tvv);
              zacc += e;
            }
          }
          ev[r] = e;
        }
        pk[2*s]   = cvtpk_bf16(ev[0], ev[1]);
        pk[2*s+1] = cvtpk_bf16(ev[2], ev[3]);
      }
      // half-wave exchange: after swap(X,Y): X=[X_lo|Y_lo], Y=[X_hi|Y_hi]
      uint a0 = pk[0], b0 = pk[2];
      asm("v_permlane32_swap_b32 %0, %1" : "+v"(a0), "+v"(b0));
      uint a1 = pk[1], b1 = pk[3];
      asm("v_permlane32_swap_b32 %0, %1" : "+v"(a1), "+v"(b1));
      uint a2 = pk[4], b2 = pk[6];
      asm("v_permlane32_swap_b32 %0, %1" : "+v"(a2), "+v"(b2));
      uint a3 = pk[5], b3 = pk[7];
      asm("v_permlane32_swap_b32 %0, %1" : "+v"(a3), "+v"(b3));
      union U8 { bf16x8 v; uint u[4]; } A0, A1;
      A0.u[0] = a0; A0.u[1] = a1; A0.u[2] = b0; A0.u[3] = b1;  // j chunk [j0, j0+16)
      A1.u[0] = a2; A1.u[1] = a3; A1.u[2] = b2; A1.u[3] = b3;  // j chunk [j0+16, j0+32)
      // AV: B[dd=l32(+32*ddg)][j = h*8+e]; D row = q, col = dd
      const ushort* v0 = vTb + (size_t)l32*NFT + j0 + h*8;
      const ushort* v1 = vTb + (size_t)(32 + l32)*NFT + j0 + h*8;
      bf16x8 bv00 = *(const bf16x8*)(v0);
      bf16x8 bv01 = *(const bf16x8*)(v0 + 16);
      bf16x8 bv10 = *(const bf16x8*)(v1);
      bf16x8 bv11 = *(const bf16x8*)(v1 + 16);
      __builtin_amdgcn_s_setprio(1);
      oc0 = __builtin_amdgcn_mfma_f32_32x32x16_bf16(A0.v, bv00, oc0, 0,0,0);
      oc0 = __builtin_amdgcn_mfma_f32_32x32x16_bf16(A1.v, bv01, oc0, 0,0,0);
      oc1 = __builtin_amdgcn_mfma_f32_32x32x16_bf16(A0.v, bv10, oc1, 0,0,0);
      oc1 = __builtin_amdgcn_mfma_f32_32x32x16_bf16(A1.v, bv11, oc1, 0,0,0);
      __builtin_amdgcn_s_setprio(0);
    };
    KF32 kc, kn2;
    load_k32(Kb, Kn, wave*32, l32, h, false, kc);
    int j0 = wave*32;
    for (; j0 + 160 <= Kn; j0 += 128){
      load_k32(Kb, Kn, j0+128, l32, h, false, kn2);
      p3(j0, false, kc);
      kc = kn2;
    }
    if (j0 + 32 <= Kn) p3(j0, false, kc);
    if (my_tail){
      KF32 kt; load_k32(Kb, Kn, tail_j0, l32, h, true, kt);
      p3(tail_j0, true, kt);
    }
    // tail AV reads vT cols < NFT (zero-padded / masked by P=0); safe.
  }

  // Z: both halves of a row sum via lane^32, then cross-wave
  zacc += __shfl_xor(zacc, 32);
  if (lane < 32) zpart[l32][wave] = zacc;
  __syncthreads();

  // O: sequential cross-wave reduction into redf (reuses ubuf)
  for (int w = 0; w < 4; w++){
    if (wave == w){
      #pragma unroll
      for (int s = 0; s < 4; s++)
        #pragma unroll
        for (int r = 0; r < 4; r++){
          int q = r + 8*s + 4*h;
          int i0 = q*64 + l32;
          if (w == 0){ redf[i0] = oc0[s*4+r];  redf[i0+32] = oc1[s*4+r]; }
          else       { redf[i0] += oc0[s*4+r]; redf[i0+32] += oc1[s*4+r]; }
        }
    }
    __syncthreads();
  }

  // store
  {
    int row = tid >> 3, d0 = (tid & 7) * 8;
    if (row < nq){
      float Z = zpart[row][0] + zpart[row][1] + zpart[row][2] + zpart[row][3];
      float zinv = Z > 0.f ? 1.f/Z : 0.f;
      uint4 ov; ushort* op = (ushort*)&ov;
      #pragma unroll
      for (int e = 0; e < 8; e++) op[e] = f2bf(redf[row*64 + d0 + e] * zinv);
      int qg = qbase + q0 + row;
      *(uint4*)(xcat + ((size_t)b*SEQ + qg)*CDIM + hh*HD + d0) = ov;
    }
  }
}

// ======================= launch =======================
extern "C" void kernel_launch(void* const* d_in, const int* in_sizes, int n_in,
                              void* d_out, int out_size, void* d_ws, size_t ws_size,
                              hipStream_t stream)
{
  const void* x        = d_in[0];
  const void* id_total = d_in[1];
  const void* mem_k    = d_in[2];
  const void* mem_v    = d_in[3];
  const void* w_qkv    = d_in[4];
  const void* w_proj   = d_in[5];
  const void* b_proj   = d_in[6];
  const void* w_idkv   = d_in[7];
  const void* b_idkv   = d_in[8];

  char* p = (char*)d_ws;
  auto carve = [&](size_t bytes)->char*{
    char* q = p; p += (bytes + 255) & ~(size_t)255; return q;
  };
  int*    modep  = (int*)   carve(256);
  ushort* xb     = (ushort*)carve(2ull*BATCH*SEQ*CDIM);
  ushort* idb    = (ushort*)carve(2ull*BATCH*NM*CDIM);
  ushort* wqkvb  = (ushort*)carve(2ull*3*CDIM*CDIM);
  ushort* wprojb = (ushort*)carve(2ull*CDIM*CDIM);
  ushort* widkvb = (ushort*)carve(2ull*IDC*CDIM);
  float*  bprojf = (float*) carve(4ull*CDIM);
  float*  bidkvf = (float*) carve(4ull*IDC);
  float*  idkvf  = (float*) carve(4ull*BATCH*NM*IDC);
  ushort* qallb  = (ushort*)carve(2ull*BATCH*NH*SEQ*HD);
  ushort* kfull  = (ushort*)carve(2ull*BATCH*NH*NFULL*HD);
  ushort* vT     = (ushort*)carve(2ull*BATCH*NH*HD*NFT);
  ushort* kmod   = (ushort*)carve(2ull*BATCH*NH*NM*HD);
  ushort* xcat   = (ushort*)carve(2ull*BATCH*SEQ*CDIM);
  ushort* vrow   = (ushort*)carve(2ull*BATCH*NH*SEQ*HD);

  dim3 blk(256,1,1);

  hipLaunchKernelGGL(detect_mode, dim3(1), blk, 0, stream, (const uint*)w_qkv, modep);
  hipLaunchKernelGGL(conv_all, dim3((NCONV+255)/256), blk, 0, stream,
                     x, id_total, w_qkv, w_proj, w_idkv, b_proj, b_idkv,
                     xb, idb, wqkvb, wprojb, widkvb, bprojf, bidkvf, modep);
  hipLaunchKernelGGL(conv_mem2, dim3(NMEM/64, BATCH*NH), blk, 0, stream,
                     mem_k, mem_v, kfull, vT, modep);
  {
    int M = BATCH*NM, Nc = IDC;
    dim3 grid((M+127)/128, (Nc+127)/128, 1);
    hipLaunchKernelGGL(gemm_idkv, grid, blk, 0, stream, idb, widkvb, bidkvf, idkvf);
  }
  {
    int M = BATCH*SEQ, Nc = 3*CDIM;
    dim3 grid((M+127)/128, (Nc+127)/128, 1);
    hipLaunchKernelGGL(gemm_qkv, grid, blk, 0, stream,
                       xb, wqkvb, idkvf, qallb, kfull, vrow, kmod, d_out, modep);
  }
  hipLaunchKernelGGL(trans_vrow, dim3((NFT-NMEM)/64, BATCH*NH), blk, 0, stream,
                     vrow, vT);
  { // fused attention, XCD-grouped remap inside the kernel
    hipLaunchKernelGGL(attn_fused, dim3(NBLK_S + NBLK_T), blk, 0, stream,
                       qallb, kfull, kmod, vT, xcat);
  }
  {
    int M = BATCH*SEQ, Nc = CDIM;
    dim3 grid((M+127)/128, (Nc+127)/128, 1);
    hipLaunchKernelGGL(gemm_proj, grid, blk, 0, stream, xcat, wprojb, bprojf, d_out, modep);
  }
}

// Round 10
// 967.873 us; speedup vs baseline: 1.2504x; 1.1624x over previous
//
#include <hip/hip_runtime.h>
#include <cstddef>

typedef unsigned int uint;
typedef unsigned short ushort;

// ---- problem constants (from reference) ----
constexpr int BATCH = 2;
constexpr int SEQ   = 2523;
constexpr int CDIM  = 768;
constexpr int NH    = 12;
constexpr int HD    = 64;
constexpr int NM    = 1682;               // template rows
constexpr int NMEM  = 4096;
constexpr int NFULL = NMEM + SEQ;         // 6619
constexpr int NFT   = 6656;               // vT padded row stride
constexpr int TOPM  = 841;                // int(0.50*1682)
constexpr int TOPS  = 1654;               // int(0.25*6619)
constexpr int IDC   = CDIM + NH;          // 780

// selection-key quantization (round 1: 8192x spreads sigma over ~10-18
// hi-buckets -> conflict-free histogram atomics; clamp +-4 is >7 sigma)
constexpr float QSC  = 8192.f;
constexpr float QINV = 1.f/8192.f;

using bf16x8 = __attribute__((ext_vector_type(8))) short;
using f32x4  = __attribute__((ext_vector_type(4))) float;
using f32x16 = __attribute__((ext_vector_type(16))) float;

__device__ __forceinline__ float bf2f(ushort u){ return __uint_as_float(((uint)u) << 16); }
__device__ __forceinline__ ushort f2bf(float f){
  uint x = __float_as_uint(f);
  x += 0x7fffu + ((x >> 16) & 1u);        // RNE
  return (ushort)(x >> 16);
}
// 16-bit monotone selection key from score (float-side clamp -> v_med3_f32)
__device__ __forceinline__ uint qkey(float s){
  float c = fminf(fmaxf(s * QSC, -32768.f), 32767.f);
  int q16 = __float2int_rn(c);
  return ((uint)(ushort)(short)q16) ^ 0x8000u;
}

// ======================= dtype detector =======================
__global__ void detect_mode(const uint* __restrict__ w, int* __restrict__ mode){
  __shared__ int cnt;
  if (threadIdx.x == 0) cnt = 0;
  __syncthreads();
  uint v = w[threadIdx.x * 97];
  uint e = (v >> 7) & 0xFFu;
  if (e >= 100u && e <= 135u) atomicAdd(&cnt, 1);
  __syncthreads();
  if (threadIdx.x == 0) mode[0] = (cnt > 128) ? 1 : 0;   // 1 = bf16, 0 = fp32
}

// ======================= fused input conversion =======================
constexpr int NX_  = BATCH*SEQ*CDIM;
constexpr int NID_ = BATCH*NM*CDIM;
constexpr int NW1_ = 3*CDIM*CDIM;
constexpr int NW2_ = CDIM*CDIM;
constexpr int NW3_ = IDC*CDIM;
constexpr int NCONV = NX_ + NID_ + NW1_ + NW2_ + NW3_ + CDIM + IDC;

__global__ void conv_all(const void* __restrict__ x, const void* __restrict__ id,
                         const void* __restrict__ w1, const void* __restrict__ w2,
                         const void* __restrict__ w3, const void* __restrict__ bp,
                         const void* __restrict__ bi,
                         ushort* __restrict__ xb, ushort* __restrict__ idb,
                         ushort* __restrict__ w1b, ushort* __restrict__ w2b,
                         ushort* __restrict__ w3b, float* __restrict__ bpf,
                         float* __restrict__ bif, const int* __restrict__ modep){
  int i = blockIdx.x*256 + threadIdx.x;
  const int mode = modep[0];
  auto cv = [&](const void* s, int j)->ushort{
    return mode ? ((const ushort*)s)[j] : f2bf(((const float*)s)[j]);
  };
  if (i < NX_ ){ xb[i]  = cv(x, i);  return; } i -= NX_;
  if (i < NID_){ idb[i] = cv(id, i); return; } i -= NID_;
  if (i < NW1_){ w1b[i] = cv(w1, i); return; } i -= NW1_;
  if (i < NW2_){ w2b[i] = cv(w2, i); return; } i -= NW2_;
  if (i < NW3_){ w3b[i] = cv(w3, i); return; } i -= NW3_;
  if (i < CDIM){ bpf[i] = mode ? bf2f(((const ushort*)bp)[i]) : ((const float*)bp)[i]; return; } i -= CDIM;
  if (i < IDC ){ bif[i] = mode ? bf2f(((const ushort*)bi)[i]) : ((const float*)bi)[i]; }
}

// mem_k -> kfull head (coalesced) AND mem_v -> vT head (LDS 64x64 transpose)
__global__ __launch_bounds__(256)
void conv_mem2(const void* __restrict__ mk, const void* __restrict__ mv,
               ushort* __restrict__ kf, ushort* __restrict__ vT,
               const int* __restrict__ modep){
  __shared__ ushort t[64][65];
  const int bh = blockIdx.y, j0 = blockIdx.x*64;
  const int mode = modep[0];
  const int tx = threadIdx.x & 63, ty = threadIdx.x >> 6;
  #pragma unroll
  for (int rr = 0; rr < 64; rr += 4){
    int j = j0 + rr + ty;
    size_t s = ((size_t)bh*NMEM + j)*HD + tx;
    ushort kv = mode ? ((const ushort*)mk)[s] : f2bf(((const float*)mk)[s]);
    kf[((size_t)bh*NFULL + j)*HD + tx] = kv;
    t[rr+ty][tx] = mode ? ((const ushort*)mv)[s] : f2bf(((const float*)mv)[s]);
  }
  __syncthreads();
  #pragma unroll
  for (int rr = 0; rr < 64; rr += 4){
    int dd = rr + ty;
    vT[((size_t)bh*HD + dd)*NFT + j0 + tx] = t[tx][dd];
  }
}

__global__ __launch_bounds__(256)
void trans_vrow(const ushort* __restrict__ vrow, ushort* __restrict__ vT){
  __shared__ ushort t[64][65];
  const int bh = blockIdx.y, j0 = blockIdx.x*64;
  const int tx = threadIdx.x & 63, ty = threadIdx.x >> 6;
  #pragma unroll
  for (int rr = 0; rr < 64; rr += 4){
    int n = j0 + rr + ty;
    ushort v = 0;                         // zero-pads vT cols [NFULL,NFT)
    if (n < SEQ) v = vrow[((size_t)bh*SEQ + n)*HD + tx];
    t[rr+ty][tx] = v;
  }
  __syncthreads();
  #pragma unroll
  for (int rr = 0; rr < 64; rr += 4){
    int dd = rr + ty;
    vT[((size_t)bh*HD + dd)*NFT + NMEM + j0 + tx] = t[tx][dd];
  }
}

// ======================= GEMM (m97 structure, 128x128 tile) =======================
#define GEMM_PROLOGUE(M_, Nc_, K_) \
  __shared__ ushort As[128][40]; \
  __shared__ ushort Bs[128][40]; \
  const int tid  = threadIdx.x; \
  const int wave = tid >> 6, lane = tid & 63; \
  const int quad = lane >> 4, l16 = lane & 15; \
  const int row0 = blockIdx.x * 128, col0 = blockIdx.y * 128; \
  const int wr = (wave >> 1) * 64, wc = (wave & 1) * 64; \
  f32x4 acc[4][4] = {}; \
  for (int k0 = 0; k0 < (K_); k0 += 32){ \
    __syncthreads(); \
    for (int c = tid; c < 512; c += 256){ \
      int r = c >> 2, ck = c & 3; \
      uint4 v = {0,0,0,0}; \
      int gr = row0 + r; \
      if (gr < (M_)) v = *(const uint4*)(A + (size_t)gr * (K_) + k0 + ck*8); \
      *(uint4*)(&As[r][ck*8]) = v; \
    } \
    for (int c = tid; c < 512; c += 256){ \
      int r = c >> 2, ck = c & 3; \
      uint4 v = {0,0,0,0}; \
      int gc = col0 + r; \
      if (gc < (Nc_)) v = *(const uint4*)(Bw + (size_t)gc * (K_) + k0 + ck*8); \
      *(uint4*)(&Bs[r][ck*8]) = v; \
    } \
    __syncthreads(); \
    bf16x8 af[4], bfr[4]; \
    _Pragma("unroll") \
    for (int i = 0; i < 4; i++) af[i]  = *(const bf16x8*)(&As[wr + 16*i + l16][quad*8]); \
    _Pragma("unroll") \
    for (int j = 0; j < 4; j++) bfr[j] = *(const bf16x8*)(&Bs[wc + 16*j + l16][quad*8]); \
    _Pragma("unroll") \
    for (int i = 0; i < 4; i++) \
      _Pragma("unroll") \
      for (int j = 0; j < 4; j++) \
        acc[i][j] = __builtin_amdgcn_mfma_f32_16x16x32_bf16(af[i], bfr[j], acc[i][j], 0, 0, 0); \
  }
// C/D layout (verified m89/m91): col = lane&15, row = (lane>>4)*4 + reg

__global__ __launch_bounds__(256)
void gemm_idkv(const ushort* __restrict__ A, const ushort* __restrict__ Bw,
               const float* __restrict__ biasf, float* __restrict__ Cf)
{
  constexpr int M = BATCH*NM, Nc = IDC, K = CDIM;
  GEMM_PROLOGUE(M, Nc, K)
  #pragma unroll
  for (int i = 0; i < 4; i++)
    #pragma unroll
    for (int j = 0; j < 4; j++)
      #pragma unroll
      for (int r = 0; r < 4; r++){
        int row = row0 + wr + 16*i + quad*4 + r;
        int col = col0 + wc + 16*j + l16;
        if (row < M && col < Nc)
          Cf[(size_t)row*Nc + col] = acc[i][j][r] + biasf[col];
      }
}

// qkv GEMM + fused epilogue: q->qallb(bf16,scaled), k->kfull tail + kmod + out_km,
// v->vrow (row-major; transposed to vT by trans_vrow) + out_vm.
__global__ __launch_bounds__(256)
void gemm_qkv(const ushort* __restrict__ A, const ushort* __restrict__ Bw,
              const float* __restrict__ idkvf, ushort* __restrict__ qallb,
              ushort* __restrict__ kfull, ushort* __restrict__ vrow,
              ushort* __restrict__ kmod, void* __restrict__ out_base,
              const int* __restrict__ modep)
{
  constexpr int M = BATCH*SEQ, Nc = 3*CDIM, K = CDIM;
  GEMM_PROLOGUE(M, Nc, K)
  const int mode = modep[0];
  constexpr size_t OKM = (size_t)BATCH*SEQ*CDIM;
  constexpr size_t OVM = OKM + (size_t)BATCH*NH*NM*HD;
  #pragma unroll
  for (int i = 0; i < 4; i++)
    #pragma unroll
    for (int j = 0; j < 4; j++)
      #pragma unroll
      for (int r = 0; r < 4; r++){
        int row = row0 + wr + 16*i + quad*4 + r;
        int col = col0 + wc + 16*j + l16;
        if (row < M && col < Nc){
          float v = acc[i][j][r];
          int b = row / SEQ, n = row - b*SEQ;
          if (col < CDIM){
            int h = col >> 6, dd = col & 63;
            qallb[((size_t)(b*NH+h)*SEQ + n)*HD + dd] = f2bf(v * 0.125f);
          } else if (col < 2*CDIM){
            int c = col - CDIM; int h = c >> 6, dd = c & 63;
            size_t bh = (size_t)b*NH + h;
            kfull[(bh*NFULL + NMEM + n)*HD + dd] = f2bf(v);
            if (n < NM){
              float idk = idkvf[((size_t)b*NM + n)*IDC + h];
              float km = v * (1.f + tanhf(idk));
              size_t o = (bh*NM + n)*HD + dd;
              kmod[o] = f2bf(km);
              if (mode) ((ushort*)out_base)[OKM + o] = f2bf(km);
              else      ((float*) out_base)[OKM + o] = km;
            }
          } else {
            int c = col - 2*CDIM; int h = c >> 6, dd = c & 63;
            size_t bh = (size_t)b*NH + h;
            float vv = v;
            if (n < NM){
              vv = v + idkvf[((size_t)b*NM + n)*IDC + NH + c];
              size_t o = (bh*NM + n)*HD + dd;
              if (mode) ((ushort*)out_base)[OVM + o] = f2bf(vv);
              else      ((float*) out_base)[OVM + o] = vv;
            }
            vrow[(bh*SEQ + n)*HD + dd] = f2bf(vv);
          }
        }
      }
}

__global__ __launch_bounds__(256)
void gemm_proj(const ushort* __restrict__ A, const ushort* __restrict__ Bw,
               const float* __restrict__ biasf, void* __restrict__ out_base,
               const int* __restrict__ modep)
{
  constexpr int M = BATCH*SEQ, Nc = CDIM, K = CDIM;
  GEMM_PROLOGUE(M, Nc, K)
  const int mode = modep[0];
  #pragma unroll
  for (int i = 0; i < 4; i++)
    #pragma unroll
    for (int j = 0; j < 4; j++)
      #pragma unroll
      for (int r = 0; r < 4; r++){
        int row = row0 + wr + 16*i + quad*4 + r;
        int col = col0 + wc + 16*j + l16;
        if (row < M && col < Nc){
          float v = acc[i][j][r] + biasf[col];
          size_t o = (size_t)row*Nc + col;
          if (mode) ((ushort*)out_base)[o] = f2bf(v);
          else      ((float*) out_base)[o] = v;
        }
      }
}

// ======================= slab-free MFMA top-k attention =======================
// Round 10: TWO passes instead of three. Round-9 counters: HBM 0.95%, MFMA
// 8.5%, VALU 52% @ 2.4 waves/SIMD -> pure VALU/latency bound; the lever is
// deleting work. Pass 2 (lo-byte rank of the boundary bucket) is replaced by
// count-exact first-come selection inside the final pass: boundary elements
// (key>>8 == bsel) are selected while atomicAdd(cnts[row]) < need. All
// boundary weights agree within e^(1/32)=3%, so swapping which `need` of
// them are kept perturbs O by ~sqrt(n)*w_b/Z ~ 2e-3 << tolerance. Threshold
// value = bucket base (s-t <= 8, exp <= 2981, bf16-safe).
//  Pass A: hi-byte histogram (packed 2 rows/word) -> bsel, need per row
//  Pass B: recompute scores; select (above-bucket | first-need-in-bucket);
//          P=exp(s-t) -> cvt_pk+permlane32 -> AV MFMA; Z alongside.

struct KF32 { bf16x8 c[4]; };           // A-operand K fragments, 4 k-chunks

__device__ __forceinline__ void load_k32(const ushort* __restrict__ Kb, int Kn,
                                         int j0, int l32, int h, bool tail, KF32& kf)
{
  int jj = j0 + l32;
  int jc = tail ? (jj < Kn ? jj : Kn-1) : jj;
  const ushort* kr = Kb + (size_t)jc*HD + h*8;
  #pragma unroll
  for (int c = 0; c < 4; c++) kf.c[c] = *(const bf16x8*)(kr + c*16);
}

__device__ __forceinline__ f32x16 score32(const bf16x8 bq[4], const KF32& kf)
{
  f32x16 acc = {};
  __builtin_amdgcn_s_setprio(1);
  #pragma unroll
  for (int c = 0; c < 4; c++)
    acc = __builtin_amdgcn_mfma_f32_32x32x16_bf16(kf.c[c], bq[c], acc, 0, 0, 0);
  __builtin_amdgcn_s_setprio(0);
  return acc;
}

__device__ __forceinline__ uint cvtpk_bf16(float lo, float hi){
  uint d;
  asm("v_cvt_pk_bf16_f32 %0, %1, %2" : "=v"(d) : "v"(lo), "v"(hi));
  return d;
}

constexpr int QT_T   = (NM + 31) / 32;          // 53
constexpr int QT_S   = (SEQ - NM + 31) / 32;    // 27
constexpr int NBLK_S = BATCH*NH*QT_S;           // 648  (long blocks first)
constexpr int NBLK_T = BATCH*NH*QT_T;           // 1272
// per-XCD decomposition: 24 heads -> 3 per XCD; 3*27=81 search + 3*53=159
// template = 240 blocks/XCD * 8 = 1920.
constexpr int XS = 3*QT_S;                      // 81

// packed 2-rows-per-word histogram: word (row&15)*257 + bucket, half row>>4.
constexpr int HISTW = 16*257;                   // 4112 words (>= 2048 redf f32)

__global__ __launch_bounds__(256)
void attn_fused(const ushort* __restrict__ qallb, const ushort* __restrict__ kfull,
                const ushort* __restrict__ kmod,  const ushort* __restrict__ vT,
                ushort* __restrict__ xcat)
{
  __shared__ uint ubuf[HISTW];          // packed hist | (late) redf 2048 f32
  __shared__ float zpart[32][4];
  __shared__ uint hi8[32], needs[32], cnts[32];
  float* redf = (float*)ubuf;

  const int tid = threadIdx.x;
  const int wave = tid >> 6, lane = tid & 63;
  const int l32 = lane & 31, h = lane >> 5;

  // ---- XCD-aware remap: physical p -> logical it so each head stays on one XCD
  int it;
  {
    int p = blockIdx.x;
    int xcd = p & 7, k = p >> 3;                // round-robin XCD model (verified r9)
    if (k < XS){ int g = k/QT_S, qt2 = k - g*QT_S; it = (xcd + 8*g)*QT_S + qt2; }
    else { int k2 = k - XS; int g = k2/QT_T, qt2 = k2 - g*QT_T;
           it = NBLK_S + (xcd + 8*g)*QT_T + qt2; }
  }
  const ushort* Kb; int Kn, ksel, vjoff, qbase, nqtot, bh, qt;
  if (it < NBLK_S){
    bh = it / QT_S; qt = it % QT_S;
    Kn = NFULL; ksel = TOPS; vjoff = 0; qbase = NM; nqtot = SEQ - NM;
    Kb = kfull + (size_t)bh * NFULL * HD;
  } else {
    it -= NBLK_S;
    bh = it / QT_T; qt = it % QT_T;
    Kn = NM; ksel = TOPM; vjoff = NMEM; qbase = 0; nqtot = NM;
    Kb = kmod + (size_t)bh * NM * HD;
  }
  const int b = bh / NH, hh = bh % NH;
  const int q0 = qt * 32;
  const int nq = min(32, nqtot - q0);
  const ushort* qb  = qallb + (size_t)bh * SEQ * HD;
  const ushort* vTb = vT + (size_t)bh * HD * NFT + vjoff;

  // tail-tile bookkeeping: tile t = j0/32 handled by wave t%4
  const bool  has_tail = (Kn & 31) != 0;
  const bool  my_tail  = has_tail && (((Kn >> 5) & 3) == wave);
  const int   tail_j0  = Kn & ~31;

  // packed-histogram lane constants (loop-invariant)
  const uint hinc = 1u << (16*(l32>>4));
  uint* hrowp = ubuf + (l32&15)*257;

  // Q fragment (B operand): lane holds Q[q=l32][k = c*16 + h*8 + e]
  bf16x8 bq[4];
  {
    int qg = qbase + q0 + l32;
    if (qg > SEQ-1) qg = SEQ-1;
    const ushort* qr = qb + (size_t)qg*HD + h*8;
    #pragma unroll
    for (int c = 0; c < 4; c++) bq[c] = *(const bf16x8*)(qr + c*16);
  }

  // ---------- pass A: hi-byte histogram (packed) ----------
  for (int i = tid; i < HISTW; i += 256) ubuf[i] = 0;
  __syncthreads();
  {
    auto pA = [&](int j0, bool tail, const KF32& kc){
      f32x16 acc = score32(bq, kc);
      #pragma unroll
      for (int s = 0; s < 4; s++)
        #pragma unroll
        for (int r = 0; r < 4; r++){
          if (!tail || (j0 + r + 8*s + 4*h) < Kn){
            uint key = qkey(acc[s*4+r]);
            atomicAdd(hrowp + (key>>8), hinc);
          }
        }
    };
    KF32 kc, kn2;
    load_k32(Kb, Kn, wave*32, l32, h, false, kc);
    int j0 = wave*32;
    for (; j0 + 160 <= Kn; j0 += 128){            // next full tile exists
      load_k32(Kb, Kn, j0+128, l32, h, false, kn2);
      pA(j0, false, kc);
      kc = kn2;
    }
    if (j0 + 32 <= Kn) pA(j0, false, kc);
    if (my_tail){
      KF32 kt; load_k32(Kb, Kn, tail_j0, l32, h, true, kt);
      pA(tail_j0, true, kt);
    }
  }
  __syncthreads();
  if (tid < 32){
    const uint sh = 16*(tid>>4);
    const uint* hrow = ubuf + (tid&15)*257;
    uint need = (uint)ksel, cum = 0; int bsel = 0;
    for (int bb = 255; bb >= 0; bb--){
      uint hc = (hrow[bb] >> sh) & 0xffffu;
      if (cum + hc >= need){ bsel = bb; need -= cum; break; }
      cum += hc;
    }
    hi8[tid] = (uint)bsel; needs[tid] = need;   // 1 <= need <= bucket count
    cnts[tid] = 0;
  }
  __syncthreads();

  // ---------- pass B: select + P + AV MFMA + Z (merged) ----------
  f32x16 oc0 = {}, oc1 = {};
  float zacc = 0.f;
  const uint  hi8q  = hi8[l32];
  const uint  needq = needs[l32];
  const float tvv   = (float)(short)(ushort)((hi8q<<8) ^ 0x8000u) * QINV;
  {
    auto pB = [&](int j0, bool tail, const KF32& kc){
      f32x16 acc = score32(bq, kc);
      // masked exp -> packed bf16 pairs (pk[2s] = {r0,r1}, pk[2s+1] = {r2,r3})
      uint pk[8];
      #pragma unroll
      for (int s = 0; s < 4; s++){
        float ev[4];
        #pragma unroll
        for (int r = 0; r < 4; r++){
          float e = 0.f;
          int jj = j0 + r + 8*s + 4*h;
          if (!tail || jj < Kn){
            float sc = acc[s*4+r];
            uint key = qkey(sc);
            uint kb = key >> 8;
            bool sel = kb > hi8q;
            if (!sel && kb == hi8q)
              sel = atomicAdd(&cnts[l32], 1u) < needq;  // count-exact, order-free
            if (sel){
              e = __expf(sc - tvv);
              zacc += e;
            }
          }
          ev[r] = e;
        }
        pk[2*s]   = cvtpk_bf16(ev[0], ev[1]);
        pk[2*s+1] = cvtpk_bf16(ev[2], ev[3]);
      }
      // half-wave exchange: after swap(X,Y): X=[X_lo|Y_lo], Y=[X_hi|Y_hi]
      uint a0 = pk[0], b0 = pk[2];
      asm("v_permlane32_swap_b32 %0, %1" : "+v"(a0), "+v"(b0));
      uint a1 = pk[1], b1 = pk[3];
      asm("v_permlane32_swap_b32 %0, %1" : "+v"(a1), "+v"(b1));
      uint a2 = pk[4], b2 = pk[6];
      asm("v_permlane32_swap_b32 %0, %1" : "+v"(a2), "+v"(b2));
      uint a3 = pk[5], b3 = pk[7];
      asm("v_permlane32_swap_b32 %0, %1" : "+v"(a3), "+v"(b3));
      union U8 { bf16x8 v; uint u[4]; } A0, A1;
      A0.u[0] = a0; A0.u[1] = a1; A0.u[2] = b0; A0.u[3] = b1;  // j [j0, j0+16)
      A1.u[0] = a2; A1.u[1] = a3; A1.u[2] = b2; A1.u[3] = b3;  // j [j0+16, j0+32)
      // AV: B[dd=l32(+32*ddg)][j = h*8+e]; D row = q, col = dd
      const ushort* v0 = vTb + (size_t)l32*NFT + j0 + h*8;
      const ushort* v1 = vTb + (size_t)(32 + l32)*NFT + j0 + h*8;
      bf16x8 bv00 = *(const bf16x8*)(v0);
      bf16x8 bv01 = *(const bf16x8*)(v0 + 16);
      bf16x8 bv10 = *(const bf16x8*)(v1);
      bf16x8 bv11 = *(const bf16x8*)(v1 + 16);
      __builtin_amdgcn_s_setprio(1);
      oc0 = __builtin_amdgcn_mfma_f32_32x32x16_bf16(A0.v, bv00, oc0, 0,0,0);
      oc0 = __builtin_amdgcn_mfma_f32_32x32x16_bf16(A1.v, bv01, oc0, 0,0,0);
      oc1 = __builtin_amdgcn_mfma_f32_32x32x16_bf16(A0.v, bv10, oc1, 0,0,0);
      oc1 = __builtin_amdgcn_mfma_f32_32x32x16_bf16(A1.v, bv11, oc1, 0,0,0);
      __builtin_amdgcn_s_setprio(0);
    };
    KF32 kc, kn2;
    load_k32(Kb, Kn, wave*32, l32, h, false, kc);
    int j0 = wave*32;
    for (; j0 + 160 <= Kn; j0 += 128){
      load_k32(Kb, Kn, j0+128, l32, h, false, kn2);
      pB(j0, false, kc);
      kc = kn2;
    }
    if (j0 + 32 <= Kn) pB(j0, false, kc);
    if (my_tail){
      KF32 kt; load_k32(Kb, Kn, tail_j0, l32, h, true, kt);
      pB(tail_j0, true, kt);
    }
    // tail AV reads vT cols < NFT (zero-padded / masked by P=0); safe.
  }

  // Z: both halves of a row sum via lane^32, then cross-wave
  zacc += __shfl_xor(zacc, 32);
  if (lane < 32) zpart[l32][wave] = zacc;
  __syncthreads();

  // O: sequential cross-wave reduction into redf (reuses ubuf)
  for (int w = 0; w < 4; w++){
    if (wave == w){
      #pragma unroll
      for (int s = 0; s < 4; s++)
        #pragma unroll
        for (int r = 0; r < 4; r++){
          int q = r + 8*s + 4*h;
          int i0 = q*64 + l32;
          if (w == 0){ redf[i0] = oc0[s*4+r];  redf[i0+32] = oc1[s*4+r]; }
          else       { redf[i0] += oc0[s*4+r]; redf[i0+32] += oc1[s*4+r]; }
        }
    }
    __syncthreads();
  }

  // store
  {
    int row = tid >> 3, d0 = (tid & 7) * 8;
    if (row < nq){
      float Z = zpart[row][0] + zpart[row][1] + zpart[row][2] + zpart[row][3];
      float zinv = Z > 0.f ? 1.f/Z : 0.f;
      uint4 ov; ushort* op = (ushort*)&ov;
      #pragma unroll
      for (int e = 0; e < 8; e++) op[e] = f2bf(redf[row*64 + d0 + e] * zinv);
      int qg = qbase + q0 + row;
      *(uint4*)(xcat + ((size_t)b*SEQ + qg)*CDIM + hh*HD + d0) = ov;
    }
  }
}

// ======================= launch =======================
extern "C" void kernel_launch(void* const* d_in, const int* in_sizes, int n_in,
                              void* d_out, int out_size, void* d_ws, size_t ws_size,
                              hipStream_t stream)
{
  const void* x        = d_in[0];
  const void* id_total = d_in[1];
  const void* mem_k    = d_in[2];
  const void* mem_v    = d_in[3];
  const void* w_qkv    = d_in[4];
  const void* w_proj   = d_in[5];
  const void* b_proj   = d_in[6];
  const void* w_idkv   = d_in[7];
  const void* b_idkv   = d_in[8];

  char* p = (char*)d_ws;
  auto carve = [&](size_t bytes)->char*{
    char* q = p; p += (bytes + 255) & ~(size_t)255; return q;
  };
  int*    modep  = (int*)   carve(256);
  ushort* xb     = (ushort*)carve(2ull*BATCH*SEQ*CDIM);
  ushort* idb    = (ushort*)carve(2ull*BATCH*NM*CDIM);
  ushort* wqkvb  = (ushort*)carve(2ull*3*CDIM*CDIM);
  ushort* wprojb = (ushort*)carve(2ull*CDIM*CDIM);
  ushort* widkvb = (ushort*)carve(2ull*IDC*CDIM);
  float*  bprojf = (float*) carve(4ull*CDIM);
  float*  bidkvf = (float*) carve(4ull*IDC);
  float*  idkvf  = (float*) carve(4ull*BATCH*NM*IDC);
  ushort* qallb  = (ushort*)carve(2ull*BATCH*NH*SEQ*HD);
  ushort* kfull  = (ushort*)carve(2ull*BATCH*NH*NFULL*HD);
  ushort* vT     = (ushort*)carve(2ull*BATCH*NH*HD*NFT);
  ushort* kmod   = (ushort*)carve(2ull*BATCH*NH*NM*HD);
  ushort* xcat   = (ushort*)carve(2ull*BATCH*SEQ*CDIM);
  ushort* vrow   = (ushort*)carve(2ull*BATCH*NH*SEQ*HD);

  dim3 blk(256,1,1);

  hipLaunchKernelGGL(detect_mode, dim3(1), blk, 0, stream, (const uint*)w_qkv, modep);
  hipLaunchKernelGGL(conv_all, dim3((NCONV+255)/256), blk, 0, stream,
                     x, id_total, w_qkv, w_proj, w_idkv, b_proj, b_idkv,
                     xb, idb, wqkvb, wprojb, widkvb, bprojf, bidkvf, modep);
  hipLaunchKernelGGL(conv_mem2, dim3(NMEM/64, BATCH*NH), blk, 0, stream,
                     mem_k, mem_v, kfull, vT, modep);
  {
    int M = BATCH*NM, Nc = IDC;
    dim3 grid((M+127)/128, (Nc+127)/128, 1);
    hipLaunchKernelGGL(gemm_idkv, grid, blk, 0, stream, idb, widkvb, bidkvf, idkvf);
  }
  {
    int M = BATCH*SEQ, Nc = 3*CDIM;
    dim3 grid((M+127)/128, (Nc+127)/128, 1);
    hipLaunchKernelGGL(gemm_qkv, grid, blk, 0, stream,
                       xb, wqkvb, idkvf, qallb, kfull, vrow, kmod, d_out, modep);
  }
  hipLaunchKernelGGL(trans_vrow, dim3((NFT-NMEM)/64, BATCH*NH), blk, 0, stream,
                     vrow, vT);
  { // fused attention, XCD-grouped remap inside the kernel
    hipLaunchKernelGGL(attn_fused, dim3(NBLK_S + NBLK_T), blk, 0, stream,
                       qallb, kfull, kmod, vT, xcat);
  }
  {
    int M = BATCH*SEQ, Nc = CDIM;
    dim3 grid((M+127)/128, (Nc+127)/128, 1);
    hipLaunchKernelGGL(gemm_proj, grid, blk, 0, stream, xcat, wprojb, bprojf, d_out, modep);
  }
}

// Round 11
// 672.259 us; speedup vs baseline: 1.8002x; 1.4397x over previous
//
#include <hip/hip_runtime.h>
#include <cstddef>

typedef unsigned int uint;
typedef unsigned short ushort;

// ---- problem constants (from reference) ----
constexpr int BATCH = 2;
constexpr int SEQ   = 2523;
constexpr int CDIM  = 768;
constexpr int NH    = 12;
constexpr int HD    = 64;
constexpr int NM    = 1682;               // template rows
constexpr int NMEM  = 4096;
constexpr int NFULL = NMEM + SEQ;         // 6619
constexpr int NFT   = 6656;               // vT padded row stride
constexpr int TOPM  = 841;                // int(0.50*1682)
constexpr int TOPS  = 1654;               // int(0.25*6619)
constexpr int IDC   = CDIM + NH;          // 780

constexpr float QSC  = 8192.f;
constexpr float QINV = 1.f/8192.f;

using bf16x8 = __attribute__((ext_vector_type(8))) short;
using f32x4  = __attribute__((ext_vector_type(4))) float;
using f32x16 = __attribute__((ext_vector_type(16))) float;

__device__ __forceinline__ float bf2f(ushort u){ return __uint_as_float(((uint)u) << 16); }
__device__ __forceinline__ ushort f2bf(float f){
  uint x = __float_as_uint(f);
  x += 0x7fffu + ((x >> 16) & 1u);        // RNE
  return (ushort)(x >> 16);
}
__device__ __forceinline__ uint qkey(float s){
  float c = fminf(fmaxf(s * QSC, -32768.f), 32767.f);
  int q16 = __float2int_rn(c);
  return ((uint)(ushort)(short)q16) ^ 0x8000u;
}

// ======================= dtype detector =======================
__global__ void detect_mode(const uint* __restrict__ w, int* __restrict__ mode){
  __shared__ int cnt;
  if (threadIdx.x == 0) cnt = 0;
  __syncthreads();
  uint v = w[threadIdx.x * 97];
  uint e = (v >> 7) & 0xFFu;
  if (e >= 100u && e <= 135u) atomicAdd(&cnt, 1);
  __syncthreads();
  if (threadIdx.x == 0) mode[0] = (cnt > 128) ? 1 : 0;   // 1 = bf16, 0 = fp32
}

// ======================= fused input conversion (8-wide stores) =======================
constexpr int NX_  = BATCH*SEQ*CDIM;
constexpr int NID_ = BATCH*NM*CDIM;
constexpr int NW1_ = 3*CDIM*CDIM;
constexpr int NW2_ = CDIM*CDIM;
constexpr int NW3_ = IDC*CDIM;
constexpr int NSUM = NX_ + NID_ + NW1_ + NW2_ + NW3_;   // all multiples of 8
constexpr int N8_  = NSUM/8;
constexpr int NCONV8 = N8_ + CDIM + IDC;

__global__ void conv_all(const void* __restrict__ x, const void* __restrict__ id,
                         const void* __restrict__ w1, const void* __restrict__ w2,
                         const void* __restrict__ w3, const void* __restrict__ bp,
                         const void* __restrict__ bi,
                         ushort* __restrict__ xb, ushort* __restrict__ idb,
                         ushort* __restrict__ w1b, ushort* __restrict__ w2b,
                         ushort* __restrict__ w3b, float* __restrict__ bpf,
                         float* __restrict__ bif, const int* __restrict__ modep){
  int t = blockIdx.x*256 + threadIdx.x;
  const int mode = modep[0];
  if (t < N8_){
    int off = t*8;
    const void* src; ushort* dst;
    if (off < NX_){ src=x; dst=xb; }
    else if ((off -= NX_) < NID_){ src=id; dst=idb; }
    else if ((off -= NID_) < NW1_){ src=w1; dst=w1b; }
    else if ((off -= NW1_) < NW2_){ src=w2; dst=w2b; }
    else { off -= NW2_; src=w3; dst=w3b; }
    ushort o[8];
    if (mode) *(uint4*)o = ((const uint4*)src)[off/8];
    else {
      #pragma unroll
      for (int e = 0; e < 8; e++) o[e] = f2bf(((const float*)src)[off+e]);
    }
    *(uint4*)(dst + off) = *(uint4*)o;
    return;
  }
  t -= N8_;
  if (t < CDIM){ bpf[t] = mode ? bf2f(((const ushort*)bp)[t]) : ((const float*)bp)[t]; return; }
  t -= CDIM;
  if (t < IDC ){ bif[t] = mode ? bf2f(((const ushort*)bi)[t]) : ((const float*)bi)[t]; }
}

// mem_k -> kfull head AND mem_v -> vT head; all global stores 16B/lane
__global__ __launch_bounds__(256)
void conv_mem2(const void* __restrict__ mk, const void* __restrict__ mv,
               ushort* __restrict__ kf, ushort* __restrict__ vT,
               const int* __restrict__ modep){
  __shared__ __align__(16) ushort tk[64][72];
  __shared__ __align__(16) ushort tv[64][72];
  const int bh = blockIdx.y, j0 = blockIdx.x*64;
  const int mode = modep[0];
  const int tid = threadIdx.x;
  for (int m = tid; m < 4096; m += 256){
    int j = m >> 6, d = m & 63;
    size_t s = ((size_t)bh*NMEM + j0 + j)*HD + d;
    tk[j][d] = mode ? ((const ushort*)mk)[s] : f2bf(((const float*)mk)[s]);
    tv[j][d] = mode ? ((const ushort*)mv)[s] : f2bf(((const float*)mv)[s]);
  }
  __syncthreads();
  for (int m = tid; m < 512; m += 256){
    int j = m >> 3, sub = m & 7;
    *(uint4*)(kf + ((size_t)bh*NFULL + j0 + j)*HD + sub*8) = *(uint4*)(&tk[j][sub*8]);
  }
  for (int m = tid; m < 512; m += 256){
    int dd = m >> 3, sub = m & 7;
    ushort tmp[8];
    #pragma unroll
    for (int e = 0; e < 8; e++) tmp[e] = tv[sub*8+e][dd];
    *(uint4*)(vT + ((size_t)bh*HD + dd)*NFT + j0 + sub*8) = *(uint4*)tmp;
  }
}

__global__ __launch_bounds__(256)
void trans_vrow(const ushort* __restrict__ vrow, ushort* __restrict__ vT){
  __shared__ __align__(16) ushort tv[64][72];
  const int bh = blockIdx.y, j0 = blockIdx.x*64;
  const int tid = threadIdx.x;
  for (int m = tid; m < 4096; m += 256){
    int j = m >> 6, d = m & 63;
    int n = j0 + j;
    ushort v = 0;                         // zero-pads vT cols [NFULL,NFT)
    if (n < SEQ) v = vrow[((size_t)bh*SEQ + n)*HD + d];
    tv[j][d] = v;
  }
  __syncthreads();
  for (int m = tid; m < 512; m += 256){
    int dd = m >> 3, sub = m & 7;
    ushort tmp[8];
    #pragma unroll
    for (int e = 0; e < 8; e++) tmp[e] = tv[sub*8+e][dd];
    *(uint4*)(vT + ((size_t)bh*HD + dd)*NFT + NMEM + j0 + sub*8) = *(uint4*)tmp;
  }
}

// ======================= GEMM macro (gemm_idkv only) =======================
#define GEMM_PROLOGUE(M_, Nc_, K_) \
  __shared__ ushort As[128][40]; \
  __shared__ ushort Bs[128][40]; \
  const int tid  = threadIdx.x; \
  const int wave = tid >> 6, lane = tid & 63; \
  const int quad = lane >> 4, l16 = lane & 15; \
  const int row0 = blockIdx.x * 128, col0 = blockIdx.y * 128; \
  const int wr = (wave >> 1) * 64, wc = (wave & 1) * 64; \
  f32x4 acc[4][4] = {}; \
  for (int k0 = 0; k0 < (K_); k0 += 32){ \
    __syncthreads(); \
    for (int c = tid; c < 512; c += 256){ \
      int r = c >> 2, ck = c & 3; \
      uint4 v = {0,0,0,0}; \
      int gr = row0 + r; \
      if (gr < (M_)) v = *(const uint4*)(A + (size_t)gr * (K_) + k0 + ck*8); \
      *(uint4*)(&As[r][ck*8]) = v; \
    } \
    for (int c = tid; c < 512; c += 256){ \
      int r = c >> 2, ck = c & 3; \
      uint4 v = {0,0,0,0}; \
      int gc = col0 + r; \
      if (gc < (Nc_)) v = *(const uint4*)(Bw + (size_t)gc * (K_) + k0 + ck*8); \
      *(uint4*)(&Bs[r][ck*8]) = v; \
    } \
    __syncthreads(); \
    bf16x8 af[4], bfr[4]; \
    _Pragma("unroll") \
    for (int i = 0; i < 4; i++) af[i]  = *(const bf16x8*)(&As[wr + 16*i + l16][quad*8]); \
    _Pragma("unroll") \
    for (int j = 0; j < 4; j++) bfr[j] = *(const bf16x8*)(&Bs[wc + 16*j + l16][quad*8]); \
    _Pragma("unroll") \
    for (int i = 0; i < 4; i++) \
      _Pragma("unroll") \
      for (int j = 0; j < 4; j++) \
        acc[i][j] = __builtin_amdgcn_mfma_f32_16x16x32_bf16(af[i], bfr[j], acc[i][j], 0, 0, 0); \
  }
// C/D layout (verified m89/m91): col = lane&15, row = (lane>>4)*4 + reg

__global__ __launch_bounds__(256)
void gemm_idkv(const ushort* __restrict__ A, const ushort* __restrict__ Bw,
               const float* __restrict__ biasf, float* __restrict__ Cf)
{
  constexpr int M = BATCH*NM, Nc = IDC, K = CDIM;
  GEMM_PROLOGUE(M, Nc, K)
  #pragma unroll
  for (int i = 0; i < 4; i++)
    #pragma unroll
    for (int j = 0; j < 4; j++)
      #pragma unroll
      for (int r = 0; r < 4; r++){
        int row = row0 + wr + 16*i + quad*4 + r;
        int col = col0 + wc + 16*j + l16;
        if (row < M && col < Nc)
          Cf[(size_t)row*Nc + col] = acc[i][j][r] + biasf[col];
      }
}

// ======================= gemm_qkv: LDS-staged wide-store epilogue =======================
// Round-11: round-10 counters showed gemm_qkv WRITE_SIZE 1.21 GB vs 49 MB
// logical (24.6x) -- per-lane 2B/4B stores each go out as ~a full 64B txn
// (bf16 28.5MBx32 + f32 20.6MBx16 = 1.24 GB, matches). Fix: stage C-tile in
// LDS, emit only uint4/float4 (16B/lane) fully-contiguous stores. fp32
// outputs staged as exact f32 half-tiles -> numerics bit-identical.
// Grid: 1D 720, XCD-grouped (each XCD owns 5 row-panels x 18 col-tiles;
// A-panel 1MB + B 3.5MB ~ per-XCD L2).
__global__ __launch_bounds__(256)
void gemm_qkv(const ushort* __restrict__ A, const ushort* __restrict__ Bw,
              const float* __restrict__ idkvf, ushort* __restrict__ qallb,
              ushort* __restrict__ kfull, ushort* __restrict__ vrow,
              ushort* __restrict__ kmod, void* __restrict__ out_base,
              const int* __restrict__ modep)
{
  constexpr int M = BATCH*SEQ, K = CDIM;
  __shared__ ushort As[128][40];
  __shared__ ushort Bs[128][40];
  __shared__ __align__(16) ushort Ct[128][136];      // 34.8KB; aliased f32 [64][136]
  float (*Cf)[136] = (float(*)[136])&Ct[0][0];

  const int tid = threadIdx.x;
  const int wave = tid >> 6, lane = tid & 63;
  const int quad = lane >> 4, l16 = lane & 15;
  const int p = blockIdx.x;
  const int bx = (p & 7)*5 + (p>>3)%5;               // row-panel 0..39
  const int by = (p>>3)/5;                           // col-tile 0..17
  const int row0 = bx*128, col0 = by*128;
  const int wr = (wave >> 1)*64, wc = (wave & 1)*64;
  f32x4 acc[4][4] = {};
  for (int k0 = 0; k0 < K; k0 += 32){
    __syncthreads();
    for (int c = tid; c < 512; c += 256){
      int r = c >> 2, ck = c & 3;
      uint4 v = {0,0,0,0};
      int gr = row0 + r;
      if (gr < M) v = *(const uint4*)(A + (size_t)gr*K + k0 + ck*8);
      *(uint4*)(&As[r][ck*8]) = v;
    }
    for (int c = tid; c < 512; c += 256){
      int r = c >> 2, ck = c & 3;
      *(uint4*)(&Bs[r][ck*8]) = *(const uint4*)(Bw + (size_t)(col0 + r)*K + k0 + ck*8);
    }
    __syncthreads();
    bf16x8 af[4], bfr[4];
    #pragma unroll
    for (int i = 0; i < 4; i++) af[i]  = *(const bf16x8*)(&As[wr + 16*i + l16][quad*8]);
    #pragma unroll
    for (int j = 0; j < 4; j++) bfr[j] = *(const bf16x8*)(&Bs[wc + 16*j + l16][quad*8]);
    #pragma unroll
    for (int i = 0; i < 4; i++)
      #pragma unroll
      for (int j = 0; j < 4; j++)
        acc[i][j] = __builtin_amdgcn_mfma_f32_16x16x32_bf16(af[i], bfr[j], acc[i][j], 0, 0, 0);
  }

  const int mode = modep[0];
  constexpr size_t OKM = (size_t)BATCH*SEQ*CDIM;
  constexpr size_t OVM = OKM + (size_t)BATCH*NH*NM*HD;
  const int region = col0 / CDIM;                    // block is region-uniform
  const int cbase  = col0 - region*CDIM;             // 0..640

  // sel: 0 = q (v*0.125), 1 = kfull (v), 2 = km (v*(1+tanh(idk))), 3 = vv (v+idv)
  auto stage_bf16 = [&](int sel){
    #pragma unroll
    for (int i = 0; i < 4; i++)
      #pragma unroll
      for (int j = 0; j < 4; j++)
        #pragma unroll
        for (int r = 0; r < 4; r++){
          int rl = wr + 16*i + quad*4 + r;
          int cl = wc + 16*j + l16;
          int row = row0 + rl;
          float v = acc[i][j][r];
          float outv = v;
          if (sel == 0) outv = v*0.125f;
          else if (sel >= 2){
            int rowc = row < M ? row : M-1;
            int b = rowc / SEQ, n = rowc - b*SEQ;
            bool hasid = (n < NM) && (row < M);
            if (sel == 2){
              int hg = (cbase + cl) >> 6;
              float idk = hasid ? idkvf[((size_t)b*NM+n)*IDC + hg] : 0.f;
              outv = v * (1.f + tanhf(idk));
            } else {
              int c = cbase + cl;
              float idv = hasid ? idkvf[((size_t)b*NM+n)*IDC + NH + c] : 0.f;
              outv = v + idv;
            }
          }
          Ct[rl][cl] = f2bf(outv);
        }
  };
  auto stage_f32 = [&](int sel, int half){           // exact f32 half-tile
    if ((wave>>1) == half){
      #pragma unroll
      for (int i = 0; i < 4; i++)
        #pragma unroll
        for (int j = 0; j < 4; j++)
          #pragma unroll
          for (int r = 0; r < 4; r++){
            int rl = 16*i + quad*4 + r;              // 0..63 local
            int cl = wc + 16*j + l16;
            int row = row0 + half*64 + rl;
            float v = acc[i][j][r];
            int rowc = row < M ? row : M-1;
            int b = rowc / SEQ, n = rowc - b*SEQ;
            bool hasid = (n < NM) && (row < M);
            float outv;
            if (sel == 2){
              int hg = (cbase + cl) >> 6;
              float idk = hasid ? idkvf[((size_t)b*NM+n)*IDC + hg] : 0.f;
              outv = v * (1.f + tanhf(idk));
            } else {
              int c = cbase + cl;
              float idv = hasid ? idkvf[((size_t)b*NM+n)*IDC + NH + c] : 0.f;
              outv = v + idv;
            }
            Cf[rl][cl] = outv;
          }
    }
  };
  // dmode 0: (bh*SEQ+n)*HD  1: (bh*NFULL+NMEM+n)*HD  2: NM-guarded (bh*NM+n)*HD
  auto copy2B = [&](ushort* dst, int dmode){
    for (int m = tid; m < 2048; m += 256){
      int h_l = m >> 10, n_l = (m >> 3) & 127, sub = m & 7;
      int row = row0 + n_l; if (row >= M) continue;
      int b = row/SEQ, n = row - b*SEQ;
      size_t bh = (size_t)b*NH + (cbase >> 6) + h_l;
      size_t e;
      if (dmode == 0)      e = (bh*SEQ + n)*HD;
      else if (dmode == 1) e = (bh*NFULL + NMEM + n)*HD;
      else { if (n >= NM) continue; e = (bh*NM + n)*HD; }
      *(uint4*)(dst + e + sub*8) = *(uint4*)(&Ct[n_l][h_l*64 + sub*8]);
    }
  };
  auto copy4B = [&](float* dst, int half){           // NM-guarded f32 out
    for (int m = tid; m < 2048; m += 256){
      int h_l = m >> 10, n_l = (m >> 4) & 63, sub = m & 15;
      int row = row0 + half*64 + n_l; if (row >= M) continue;
      int b = row/SEQ, n = row - b*SEQ; if (n >= NM) continue;
      size_t e = (((size_t)b*NH + (cbase>>6) + h_l)*NM + n)*HD + sub*4;
      *(float4*)(dst + e) = *(float4*)(&Cf[n_l][h_l*64 + sub*4]);
    }
  };

  if (region == 0){
    stage_bf16(0); __syncthreads(); copy2B(qallb, 0);
  } else if (region == 1){
    stage_bf16(1); __syncthreads(); copy2B(kfull, 1); __syncthreads();
    stage_bf16(2); __syncthreads(); copy2B(kmod, 2);
    if (mode){
      copy2B((ushort*)out_base + OKM, 2);
    } else {
      __syncthreads(); stage_f32(2,0); __syncthreads(); copy4B((float*)out_base + OKM, 0);
      __syncthreads(); stage_f32(2,1); __syncthreads(); copy4B((float*)out_base + OKM, 1);
    }
  } else {
    stage_bf16(3); __syncthreads(); copy2B(vrow, 0);
    if (mode){
      copy2B((ushort*)out_base + OVM, 2);
    } else {
      __syncthreads(); stage_f32(3,0); __syncthreads(); copy4B((float*)out_base + OVM, 0);
      __syncthreads(); stage_f32(3,1); __syncthreads(); copy4B((float*)out_base + OVM, 1);
    }
  }
}

// ======================= gemm_proj: staged wide-store epilogue =======================
__global__ __launch_bounds__(256)
void gemm_proj(const ushort* __restrict__ A, const ushort* __restrict__ Bw,
               const float* __restrict__ biasf, void* __restrict__ out_base,
               const int* __restrict__ modep)
{
  constexpr int M = BATCH*SEQ, K = CDIM;
  __shared__ ushort As[128][40];
  __shared__ ushort Bs[128][40];
  __shared__ __align__(16) ushort Ct[128][136];
  float (*Cf)[136] = (float(*)[136])&Ct[0][0];
  const int tid = threadIdx.x;
  const int wave = tid >> 6, lane = tid & 63;
  const int quad = lane >> 4, l16 = lane & 15;
  const int p = blockIdx.x;
  const int bx = (p & 7)*5 + (p>>3)%5;               // 0..39
  const int by = (p>>3)/5;                           // 0..5
  const int row0 = bx*128, col0 = by*128;
  const int wr = (wave >> 1)*64, wc = (wave & 1)*64;
  f32x4 acc[4][4] = {};
  for (int k0 = 0; k0 < K; k0 += 32){
    __syncthreads();
    for (int c = tid; c < 512; c += 256){
      int r = c >> 2, ck = c & 3;
      uint4 v = {0,0,0,0};
      int gr = row0 + r;
      if (gr < M) v = *(const uint4*)(A + (size_t)gr*K + k0 + ck*8);
      *(uint4*)(&As[r][ck*8]) = v;
    }
    for (int c = tid; c < 512; c += 256){
      int r = c >> 2, ck = c & 3;
      *(uint4*)(&Bs[r][ck*8]) = *(const uint4*)(Bw + (size_t)(col0 + r)*K + k0 + ck*8);
    }
    __syncthreads();
    bf16x8 af[4], bfr[4];
    #pragma unroll
    for (int i = 0; i < 4; i++) af[i]  = *(const bf16x8*)(&As[wr + 16*i + l16][quad*8]);
    #pragma unroll
    for (int j = 0; j < 4; j++) bfr[j] = *(const bf16x8*)(&Bs[wc + 16*j + l16][quad*8]);
    #pragma unroll
    for (int i = 0; i < 4; i++)
      #pragma unroll
      for (int j = 0; j < 4; j++)
        acc[i][j] = __builtin_amdgcn_mfma_f32_16x16x32_bf16(af[i], bfr[j], acc[i][j], 0, 0, 0);
  }
  const int mode = modep[0];
  if (mode){
    #pragma unroll
    for (int i = 0; i < 4; i++)
      #pragma unroll
      for (int j = 0; j < 4; j++)
        #pragma unroll
        for (int r = 0; r < 4; r++){
          int rl = wr + 16*i + quad*4 + r, cl = wc + 16*j + l16;
          Ct[rl][cl] = f2bf(acc[i][j][r] + biasf[col0 + cl]);
        }
    __syncthreads();
    ushort* outp = (ushort*)out_base;
    for (int m = tid; m < 2048; m += 256){
      int n_l = m >> 4, sub = m & 15;
      int row = row0 + n_l; if (row >= M) continue;
      *(uint4*)(outp + (size_t)row*CDIM + col0 + sub*8) = *(uint4*)(&Ct[n_l][sub*8]);
    }
  } else {
    float* outp = (float*)out_base;
    #pragma unroll
    for (int half = 0; half < 2; half++){
      if ((wave>>1) == half){
        #pragma unroll
        for (int i = 0; i < 4; i++)
          #pragma unroll
          for (int j = 0; j < 4; j++)
            #pragma unroll
            for (int r = 0; r < 4; r++){
              int rl = 16*i + quad*4 + r, cl = wc + 16*j + l16;
              Cf[rl][cl] = acc[i][j][r] + biasf[col0 + cl];
            }
      }
      __syncthreads();
      for (int m = tid; m < 2048; m += 256){
        int n_l = m >> 5, sub = m & 31;
        int row = row0 + half*64 + n_l; if (row >= M) continue;
        *(float4*)(outp + (size_t)row*CDIM + col0 + sub*4) = *(float4*)(&Cf[n_l][sub*4]);
      }
      __syncthreads();
    }
  }
}

// ======================= slab-free MFMA top-k attention (round 10, unchanged) =======================
struct KF32 { bf16x8 c[4]; };           // A-operand K fragments, 4 k-chunks

__device__ __forceinline__ void load_k32(const ushort* __restrict__ Kb, int Kn,
                                         int j0, int l32, int h, bool tail, KF32& kf)
{
  int jj = j0 + l32;
  int jc = tail ? (jj < Kn ? jj : Kn-1) : jj;
  const ushort* kr = Kb + (size_t)jc*HD + h*8;
  #pragma unroll
  for (int c = 0; c < 4; c++) kf.c[c] = *(const bf16x8*)(kr + c*16);
}

__device__ __forceinline__ f32x16 score32(const bf16x8 bq[4], const KF32& kf)
{
  f32x16 acc = {};
  __builtin_amdgcn_s_setprio(1);
  #pragma unroll
  for (int c = 0; c < 4; c++)
    acc = __builtin_amdgcn_mfma_f32_32x32x16_bf16(kf.c[c], bq[c], acc, 0, 0, 0);
  __builtin_amdgcn_s_setprio(0);
  return acc;
}

__device__ __forceinline__ uint cvtpk_bf16(float lo, float hi){
  uint d;
  asm("v_cvt_pk_bf16_f32 %0, %1, %2" : "=v"(d) : "v"(lo), "v"(hi));
  return d;
}

constexpr int QT_T   = (NM + 31) / 32;          // 53
constexpr int QT_S   = (SEQ - NM + 31) / 32;    // 27
constexpr int NBLK_S = BATCH*NH*QT_S;           // 648
constexpr int NBLK_T = BATCH*NH*QT_T;           // 1272
constexpr int XS = 3*QT_S;                      // 81

constexpr int HISTW = 16*257;                   // 4112 words (>= 2048 redf f32)

__global__ __launch_bounds__(256)
void attn_fused(const ushort* __restrict__ qallb, const ushort* __restrict__ kfull,
                const ushort* __restrict__ kmod,  const ushort* __restrict__ vT,
                ushort* __restrict__ xcat)
{
  __shared__ uint ubuf[HISTW];          // packed hist | (late) redf 2048 f32
  __shared__ float zpart[32][4];
  __shared__ uint hi8[32], needs[32], cnts[32];
  float* redf = (float*)ubuf;

  const int tid = threadIdx.x;
  const int wave = tid >> 6, lane = tid & 63;
  const int l32 = lane & 31, h = lane >> 5;

  int it;
  {
    int p = blockIdx.x;
    int xcd = p & 7, k = p >> 3;
    if (k < XS){ int g = k/QT_S, qt2 = k - g*QT_S; it = (xcd + 8*g)*QT_S + qt2; }
    else { int k2 = k - XS; int g = k2/QT_T, qt2 = k2 - g*QT_T;
           it = NBLK_S + (xcd + 8*g)*QT_T + qt2; }
  }
  const ushort* Kb; int Kn, ksel, vjoff, qbase, nqtot, bh, qt;
  if (it < NBLK_S){
    bh = it / QT_S; qt = it % QT_S;
    Kn = NFULL; ksel = TOPS; vjoff = 0; qbase = NM; nqtot = SEQ - NM;
    Kb = kfull + (size_t)bh * NFULL * HD;
  } else {
    it -= NBLK_S;
    bh = it / QT_T; qt = it % QT_T;
    Kn = NM; ksel = TOPM; vjoff = NMEM; qbase = 0; nqtot = NM;
    Kb = kmod + (size_t)bh * NM * HD;
  }
  const int b = bh / NH, hh = bh % NH;
  const int q0 = qt * 32;
  const int nq = min(32, nqtot - q0);
  const ushort* qb  = qallb + (size_t)bh * SEQ * HD;
  const ushort* vTb = vT + (size_t)bh * HD * NFT + vjoff;

  const bool  has_tail = (Kn & 31) != 0;
  const bool  my_tail  = has_tail && (((Kn >> 5) & 3) == wave);
  const int   tail_j0  = Kn & ~31;

  const uint hinc = 1u << (16*(l32>>4));
  uint* hrowp = ubuf + (l32&15)*257;

  bf16x8 bq[4];
  {
    int qg = qbase + q0 + l32;
    if (qg > SEQ-1) qg = SEQ-1;
    const ushort* qr = qb + (size_t)qg*HD + h*8;
    #pragma unroll
    for (int c = 0; c < 4; c++) bq[c] = *(const bf16x8*)(qr + c*16);
  }

  // ---------- pass A: hi-byte histogram (packed) ----------
  for (int i = tid; i < HISTW; i += 256) ubuf[i] = 0;
  __syncthreads();
  {
    auto pA = [&](int j0, bool tail, const KF32& kc){
      f32x16 acc = score32(bq, kc);
      #pragma unroll
      for (int s = 0; s < 4; s++)
        #pragma unroll
        for (int r = 0; r < 4; r++){
          if (!tail || (j0 + r + 8*s + 4*h) < Kn){
            uint key = qkey(acc[s*4+r]);
            atomicAdd(hrowp + (key>>8), hinc);
          }
        }
    };
    KF32 kc, kn2;
    load_k32(Kb, Kn, wave*32, l32, h, false, kc);
    int j0 = wave*32;
    for (; j0 + 160 <= Kn; j0 += 128){
      load_k32(Kb, Kn, j0+128, l32, h, false, kn2);
      pA(j0, false, kc);
      kc = kn2;
    }
    if (j0 + 32 <= Kn) pA(j0, false, kc);
    if (my_tail){
      KF32 kt; load_k32(Kb, Kn, tail_j0, l32, h, true, kt);
      pA(tail_j0, true, kt);
    }
  }
  __syncthreads();
  if (tid < 32){
    const uint sh = 16*(tid>>4);
    const uint* hrow = ubuf + (tid&15)*257;
    uint need = (uint)ksel, cum = 0; int bsel = 0;
    for (int bb = 255; bb >= 0; bb--){
      uint hc = (hrow[bb] >> sh) & 0xffffu;
      if (cum + hc >= need){ bsel = bb; need -= cum; break; }
      cum += hc;
    }
    hi8[tid] = (uint)bsel; needs[tid] = need;
    cnts[tid] = 0;
  }
  __syncthreads();

  // ---------- pass B: select + P + AV MFMA + Z (merged) ----------
  f32x16 oc0 = {}, oc1 = {};
  float zacc = 0.f;
  const uint  hi8q  = hi8[l32];
  const uint  needq = needs[l32];
  const float tvv   = (float)(short)(ushort)((hi8q<<8) ^ 0x8000u) * QINV;
  {
    auto pB = [&](int j0, bool tail, const KF32& kc){
      f32x16 acc = score32(bq, kc);
      uint pk[8];
      #pragma unroll
      for (int s = 0; s < 4; s++){
        float ev[4];
        #pragma unroll
        for (int r = 0; r < 4; r++){
          float e = 0.f;
          int jj = j0 + r + 8*s + 4*h;
          if (!tail || jj < Kn){
            float sc = acc[s*4+r];
            uint key = qkey(sc);
            uint kb = key >> 8;
            bool sel = kb > hi8q;
            if (!sel && kb == hi8q)
              sel = atomicAdd(&cnts[l32], 1u) < needq;
            if (sel){
              e = __expf(sc - tvv);
              zacc += e;
            }
          }
          ev[r] = e;
        }
        pk[2*s]   = cvtpk_bf16(ev[0], ev[1]);
        pk[2*s+1] = cvtpk_bf16(ev[2], ev[3]);
      }
      uint a0 = pk[0], b0 = pk[2];
      asm("v_permlane32_swap_b32 %0, %1" : "+v"(a0), "+v"(b0));
      uint a1 = pk[1], b1 = pk[3];
      asm("v_permlane32_swap_b32 %0, %1" : "+v"(a1), "+v"(b1));
      uint a2 = pk[4], b2 = pk[6];
      asm("v_permlane32_swap_b32 %0, %1" : "+v"(a2), "+v"(b2));
      uint a3 = pk[5], b3 = pk[7];
      asm("v_permlane32_swap_b32 %0, %1" : "+v"(a3), "+v"(b3));
      union U8 { bf16x8 v; uint u[4]; } A0, A1;
      A0.u[0] = a0; A0.u[1] = a1; A0.u[2] = b0; A0.u[3] = b1;
      A1.u[0] = a2; A1.u[1] = a3; A1.u[2] = b2; A1.u[3] = b3;
      const ushort* v0 = vTb + (size_t)l32*NFT + j0 + h*8;
      const ushort* v1 = vTb + (size_t)(32 + l32)*NFT + j0 + h*8;
      bf16x8 bv00 = *(const bf16x8*)(v0);
      bf16x8 bv01 = *(const bf16x8*)(v0 + 16);
      bf16x8 bv10 = *(const bf16x8*)(v1);
      bf16x8 bv11 = *(const bf16x8*)(v1 + 16);
      __builtin_amdgcn_s_setprio(1);
      oc0 = __builtin_amdgcn_mfma_f32_32x32x16_bf16(A0.v, bv00, oc0, 0,0,0);
      oc0 = __builtin_amdgcn_mfma_f32_32x32x16_bf16(A1.v, bv01, oc0, 0,0,0);
      oc1 = __builtin_amdgcn_mfma_f32_32x32x16_bf16(A0.v, bv10, oc1, 0,0,0);
      oc1 = __builtin_amdgcn_mfma_f32_32x32x16_bf16(A1.v, bv11, oc1, 0,0,0);
      __builtin_amdgcn_s_setprio(0);
    };
    KF32 kc, kn2;
    load_k32(Kb, Kn, wave*32, l32, h, false, kc);
    int j0 = wave*32;
    for (; j0 + 160 <= Kn; j0 += 128){
      load_k32(Kb, Kn, j0+128, l32, h, false, kn2);
      pB(j0, false, kc);
      kc = kn2;
    }
    if (j0 + 32 <= Kn) pB(j0, false, kc);
    if (my_tail){
      KF32 kt; load_k32(Kb, Kn, tail_j0, l32, h, true, kt);
      pB(tail_j0, true, kt);
    }
  }

  zacc += __shfl_xor(zacc, 32);
  if (lane < 32) zpart[l32][wave] = zacc;
  __syncthreads();

  for (int w = 0; w < 4; w++){
    if (wave == w){
      #pragma unroll
      for (int s = 0; s < 4; s++)
        #pragma unroll
        for (int r = 0; r < 4; r++){
          int q = r + 8*s + 4*h;
          int i0 = q*64 + l32;
          if (w == 0){ redf[i0] = oc0[s*4+r];  redf[i0+32] = oc1[s*4+r]; }
          else       { redf[i0] += oc0[s*4+r]; redf[i0+32] += oc1[s*4+r]; }
        }
    }
    __syncthreads();
  }

  {
    int row = tid >> 3, d0 = (tid & 7) * 8;
    if (row < nq){
      float Z = zpart[row][0] + zpart[row][1] + zpart[row][2] + zpart[row][3];
      float zinv = Z > 0.f ? 1.f/Z : 0.f;
      uint4 ov; ushort* op = (ushort*)&ov;
      #pragma unroll
      for (int e = 0; e < 8; e++) op[e] = f2bf(redf[row*64 + d0 + e] * zinv);
      int qg = qbase + q0 + row;
      *(uint4*)(xcat + ((size_t)b*SEQ + qg)*CDIM + hh*HD + d0) = ov;
    }
  }
}

// ======================= launch =======================
extern "C" void kernel_launch(void* const* d_in, const int* in_sizes, int n_in,
                              void* d_out, int out_size, void* d_ws, size_t ws_size,
                              hipStream_t stream)
{
  const void* x        = d_in[0];
  const void* id_total = d_in[1];
  const void* mem_k    = d_in[2];
  const void* mem_v    = d_in[3];
  const void* w_qkv    = d_in[4];
  const void* w_proj   = d_in[5];
  const void* b_proj   = d_in[6];
  const void* w_idkv   = d_in[7];
  const void* b_idkv   = d_in[8];

  char* p = (char*)d_ws;
  auto carve = [&](size_t bytes)->char*{
    char* q = p; p += (bytes + 255) & ~(size_t)255; return q;
  };
  int*    modep  = (int*)   carve(256);
  ushort* xb     = (ushort*)carve(2ull*BATCH*SEQ*CDIM);
  ushort* idb    = (ushort*)carve(2ull*BATCH*NM*CDIM);
  ushort* wqkvb  = (ushort*)carve(2ull*3*CDIM*CDIM);
  ushort* wprojb = (ushort*)carve(2ull*CDIM*CDIM);
  ushort* widkvb = (ushort*)carve(2ull*IDC*CDIM);
  float*  bprojf = (float*) carve(4ull*CDIM);
  float*  bidkvf = (float*) carve(4ull*IDC);
  float*  idkvf  = (float*) carve(4ull*BATCH*NM*IDC);
  ushort* qallb  = (ushort*)carve(2ull*BATCH*NH*SEQ*HD);
  ushort* kfull  = (ushort*)carve(2ull*BATCH*NH*NFULL*HD);
  ushort* vT     = (ushort*)carve(2ull*BATCH*NH*HD*NFT);
  ushort* kmod   = (ushort*)carve(2ull*BATCH*NH*NM*HD);
  ushort* xcat   = (ushort*)carve(2ull*BATCH*SEQ*CDIM);
  ushort* vrow   = (ushort*)carve(2ull*BATCH*NH*SEQ*HD);

  dim3 blk(256,1,1);

  hipLaunchKernelGGL(detect_mode, dim3(1), blk, 0, stream, (const uint*)w_qkv, modep);
  hipLaunchKernelGGL(conv_all, dim3((NCONV8+255)/256), blk, 0, stream,
                     x, id_total, w_qkv, w_proj, w_idkv, b_proj, b_idkv,
                     xb, idb, wqkvb, wprojb, widkvb, bprojf, bidkvf, modep);
  hipLaunchKernelGGL(conv_mem2, dim3(NMEM/64, BATCH*NH), blk, 0, stream,
                     mem_k, mem_v, kfull, vT, modep);
  {
    int M = BATCH*NM, Nc = IDC;
    dim3 grid((M+127)/128, (Nc+127)/128, 1);
    hipLaunchKernelGGL(gemm_idkv, grid, blk, 0, stream, idb, widkvb, bidkvf, idkvf);
  }
  hipLaunchKernelGGL(gemm_qkv, dim3(720), blk, 0, stream,
                     xb, wqkvb, idkvf, qallb, kfull, vrow, kmod, d_out, modep);
  hipLaunchKernelGGL(trans_vrow, dim3((NFT-NMEM)/64, BATCH*NH), blk, 0, stream,
                     vrow, vT);
  hipLaunchKernelGGL(attn_fused, dim3(NBLK_S + NBLK_T), blk, 0, stream,
                     qallb, kfull, kmod, vT, xcat);
  hipLaunchKernelGGL(gemm_proj, dim3(240), blk, 0, stream,
                     xcat, wprojb, bprojf, d_out, modep);
}